// Round 4
// baseline (757.496 us; speedup 1.0000x reference)
//
#include <hip/hip_runtime.h>
#include <hip/hip_bf16.h>

#define DEV static __device__ __forceinline__

constexpr int N_NODES = 20000;
constexpr int N_EDGES = 320000;
constexpr int NFEAT = 128;
constexpr int NHID = 64;
constexpr int NCLASS = 16;
constexpr int HEADS = 4;
constexpr int HD = HEADS * NHID;   // 256
constexpr float EPSV = 1e-5f;
constexpr float SLOPE = 0.2f;
constexpr float SP1 = 1.3132616875182228f;   // softplus(1.0)

DEV float bf2f(__hip_bfloat16 v) { return __bfloat162float(v); }
DEV float bfbits2f(unsigned short b) { return __uint_as_float(((unsigned)b) << 16); }
DEV float lrelu(float v) { return v > 0.f ? v : SLOPE * v; }
DEV int clampn(int v) { return min(max(v, 0), N_NODES - 1); }

DEV float tof(float v) { return v; }
DEV float tof(__hip_bfloat16 v) { return __bfloat162float(v); }

// flag-selected float-input loader (f32 flag is wave-uniform)
DEV float ldf(const void* p, int i, int f32) {
  return f32 ? ((const float*)p)[i] : bf2f(((const __hip_bfloat16*)p)[i]);
}
DEV int eload(const int* e32, int is64, int idx) {
  if (is64) return (int)(((const long long*)e32)[idx]);
  return e32[idx];
}

DEV float wsum(float v) {
#pragma unroll
  for (int m = 32; m > 0; m >>= 1) v += __shfl_xor(v, m, 64);
  return v;
}
DEV float wmax(float v) {
#pragma unroll
  for (int m = 32; m > 0; m >>= 1) v = fmaxf(v, __shfl_xor(v, m, 64));
  return v;
}

// ---------------- dtype probes ----------------
// flag[0]: edge_index is int64 (high dwords of first 64 elements all zero)
// flag[1]: float inputs are fp32 (low-ushort-of-dword exponent junk detected in x)
__global__ void k_detect(const int* __restrict__ edge, const unsigned* __restrict__ xw,
                         int* __restrict__ flag) {
  int t = threadIdx.x;  // 64 threads
  int v = edge[2 * t + 1];
  unsigned long long nz = __ballot(v != 0);
  int bad = 0;
#pragma unroll
  for (int j = 0; j < 4; ++j) {
    unsigned w = xw[t * 4 + j];
    unsigned lu = w & 0xFFFFu;
    unsigned ex = (lu >> 7) & 0xFFu;
    if (ex >= 0x90u) bad = 1;  // |bf16| >= 2^17: impossible for real x (~N(0,1))
  }
  unsigned long long anybad = __ballot(bad != 0);
  if (t == 0) {
    flag[0] = (nz == 0ULL) ? 1 : 0;
    flag[1] = (anybad != 0ULL) ? 1 : 0;
  }
}

// ---------------- CSR build ----------------
__global__ void k_hist(const int* __restrict__ edge, const int* __restrict__ flag,
                       int* __restrict__ counts) {
  int e = blockIdx.x * blockDim.x + threadIdx.x;
  if (e < N_EDGES) {
    int d = clampn(eload(edge, flag[0], N_EDGES + e));
    atomicAdd(&counts[d], 1);
  }
}

__global__ __launch_bounds__(1024) void k_scan(const int* __restrict__ counts,
                                               int* __restrict__ rowptr,
                                               int* __restrict__ cursor) {
  __shared__ int part[1024];
  int t = threadIdx.x;
  const int CH = (N_NODES + 1023) / 1024;  // 20
  int b = t * CH, e = min(b + CH, N_NODES);
  int s = 0;
  for (int i = b; i < e; ++i) s += counts[i];
  part[t] = s;
  __syncthreads();
  for (int off = 1; off < 1024; off <<= 1) {
    int v = (t >= off) ? part[t - off] : 0;
    __syncthreads();
    part[t] += v;
    __syncthreads();
  }
  int run = (t == 0) ? 0 : part[t - 1];
  for (int i = b; i < e; ++i) {
    rowptr[i] = run;
    cursor[i] = run;
    run += counts[i];
  }
  if (t == 1023) rowptr[N_NODES] = N_EDGES;
}

__global__ void k_scatter(const int* __restrict__ edge, const int* __restrict__ flag,
                          int* __restrict__ cursor, int* __restrict__ ssort) {
  int e = blockIdx.x * blockDim.x + threadIdx.x;
  if (e < N_EDGES) {
    int is64 = flag[0];
    int s = clampn(eload(edge, is64, e));
    int d = clampn(eload(edge, is64, N_EDGES + e));
    int pos = atomicAdd(&cursor[d], 1);
    if (pos >= 0 && pos < N_EDGES) ssort[pos] = s;
  }
}

// ---------------- encoder: Y = relu(x @ W_enc + b_enc); X = Y ----------------
__global__ __launch_bounds__(256) void k_encoder(const void* __restrict__ x,
                                                 const void* __restrict__ W_enc,
                                                 const void* __restrict__ b_enc,
                                                 const int* __restrict__ flag,
                                                 float* __restrict__ X, float* __restrict__ Y) {
  __shared__ float Wl[NFEAT * NHID];  // 32 KB
  int f32 = flag[1];
  int tid = threadIdx.x;
  for (int i = tid; i < NFEAT * NHID; i += 256) Wl[i] = ldf(W_enc, i, f32);
  __syncthreads();
  int wave = tid >> 6, lane = tid & 63;
  const int NPB = 16;
  int base = blockIdx.x * NPB;
  float bias = ldf(b_enc, lane, f32);

  auto run = [&](auto xp) {
    for (int ni = wave; ni < NPB; ni += 4) {
      int n = base + ni;
      if (n >= N_NODES) continue;
      auto xr = xp + (size_t)n * NFEAT;
      float acc = 0.f;
#pragma unroll 8
      for (int k = 0; k < NFEAT; ++k)
        acc = fmaf(tof(xr[k]), Wl[k * NHID + lane], acc);
      float yv = fmaxf(acc + bias, 0.f);
      Y[(size_t)n * NHID + lane] = yv;
      X[(size_t)n * NHID + lane] = yv;
    }
  };
  if (f32) run((const float*)x);
  else     run((const __hip_bfloat16*)x);
}

// ---------------- per-layer projection: h = X @ W_gat (bf16 out), a_src/a_dst ----------------
__global__ __launch_bounds__(256) void k_proj(const float* __restrict__ X,
                                              const void* __restrict__ W_gat,
                                              const void* __restrict__ att_src,
                                              const void* __restrict__ att_dst,
                                              const int* __restrict__ flag,
                                              unsigned short* __restrict__ hb,
                                              float* __restrict__ a_src,
                                              float* __restrict__ a_dst) {
  __shared__ float Wl[NHID * HD];  // 64 KB exactly
  int f32 = flag[1];
  int tid = threadIdx.x;
  for (int i = tid; i < NHID * HD; i += 256) Wl[i] = ldf(W_gat, i, f32);
  __syncthreads();
  float asw = ldf(att_src, tid, f32);
  float adw = ldf(att_dst, tid, f32);
  int lane = tid & 63;
  int head = tid >> 6;
  const int NPB = 32;
  int base = blockIdx.x * NPB;
  for (int ni = 0; ni < NPB; ++ni) {
    int n = base + ni;
    const float* xr = X + (size_t)n * NHID;
    float acc = 0.f;
#pragma unroll 8
    for (int k = 0; k < NHID; ++k)
      acc = fmaf(xr[k], Wl[k * HD + tid], acc);
    hb[(size_t)n * HD + tid] = (unsigned short)(__bfloat16_as_ushort(__float2bfloat16(acc)));
    float s1 = wsum(acc * asw);
    float s2 = wsum(acc * adw);
    if (lane == 0) {
      a_src[n * HEADS + head] = s1;
      a_dst[n * HEADS + head] = s2;
    }
  }
}

// ---------------- per-layer: softmax-aggregate + ELU + mean + GraphCON + rms ----------------
__global__ __launch_bounds__(256) void k_layer(const unsigned short* __restrict__ hb,
                                               const float* __restrict__ a_src,
                                               const float* __restrict__ a_dst,
                                               const int* __restrict__ rowptr,
                                               const int* __restrict__ srcs,
                                               const void* __restrict__ b_gat,
                                               const int* __restrict__ flag,
                                               float* __restrict__ X, float* __restrict__ Y) {
  int wave = threadIdx.x >> 6, lane = threadIdx.x & 63;
  int f32 = flag[1];
  int d = blockIdx.x * 4 + wave;
  if (d >= N_NODES) return;
  int beg = rowptr[d];
  int end = rowptr[d + 1];
  beg = min(max(beg, 0), N_EDGES);
  end = min(max(end, beg), N_EDGES);
  int deg = end - beg;
  int tot = deg + 1;  // + self loop
  const float4 adv = *(const float4*)(a_dst + d * 4);

  // phase 1: per-head max over incoming edges (edge-parallel across lanes)
  float mx0 = -1e30f, mx1 = -1e30f, mx2 = -1e30f, mx3 = -1e30f;
  for (int i = lane; i < tot; i += 64) {
    int s = (i < deg) ? clampn(srcs[beg + i]) : d;
    const float4 ar = *(const float4*)(a_src + s * 4);
    mx0 = fmaxf(mx0, lrelu(ar.x + adv.x));
    mx1 = fmaxf(mx1, lrelu(ar.y + adv.y));
    mx2 = fmaxf(mx2, lrelu(ar.z + adv.z));
    mx3 = fmaxf(mx3, lrelu(ar.w + adv.w));
  }
  mx0 = wmax(mx0); mx1 = wmax(mx1); mx2 = wmax(mx2); mx3 = wmax(mx3);

  // phase 2: per-head sum(exp)
  float sm0 = 0.f, sm1 = 0.f, sm2 = 0.f, sm3 = 0.f;
  for (int i = lane; i < tot; i += 64) {
    int s = (i < deg) ? clampn(srcs[beg + i]) : d;
    const float4 ar = *(const float4*)(a_src + s * 4);
    sm0 += __expf(lrelu(ar.x + adv.x) - mx0);
    sm1 += __expf(lrelu(ar.y + adv.y) - mx1);
    sm2 += __expf(lrelu(ar.z + adv.z) - mx2);
    sm3 += __expf(lrelu(ar.w + adv.w) - mx3);
  }
  sm0 = wsum(sm0); sm1 = wsum(sm1); sm2 = wsum(sm2); sm3 = wsum(sm3);
  float inv0 = 1.f / (sm0 + 1e-16f), inv1 = 1.f / (sm1 + 1e-16f);
  float inv2 = 1.f / (sm2 + 1e-16f), inv3 = 1.f / (sm3 + 1e-16f);

  // per-lane head selection (lane l covers conv columns 4l..4l+3, all in head l>>4)
  int hd = lane >> 4;
  float adh = (hd == 0) ? adv.x : (hd == 1) ? adv.y : (hd == 2) ? adv.z : adv.w;
  float mxh = (hd == 0) ? mx0 : (hd == 1) ? mx1 : (hd == 2) ? mx2 : mx3;
  float invh = (hd == 0) ? inv0 : (hd == 1) ? inv1 : (hd == 2) ? inv2 : inv3;

  // phase 3: feature-parallel weighted aggregation (bf16 h)
  float4 acc = make_float4(0.f, 0.f, 0.f, 0.f);
  for (int i = 0; i < tot; ++i) {
    int s = (i < deg) ? clampn(srcs[beg + i]) : d;
    float ev = lrelu(a_src[s * 4 + hd] + adh);
    float alpha = __expf(ev - mxh) * invh;
    const ushort4 hv = *(const ushort4*)(hb + (size_t)s * HD + lane * 4);
    acc.x = fmaf(bfbits2f(hv.x), alpha, acc.x);
    acc.y = fmaf(bfbits2f(hv.y), alpha, acc.y);
    acc.z = fmaf(bfbits2f(hv.z), alpha, acc.z);
    acc.w = fmaf(bfbits2f(hv.w), alpha, acc.w);
  }

  // bias + ELU + mean-over-4 (== reshape(N,64,4).mean(-1) at element `lane`)
  float c0 = acc.x + ldf(b_gat, lane * 4 + 0, f32);
  float c1 = acc.y + ldf(b_gat, lane * 4 + 1, f32);
  float c2 = acc.z + ldf(b_gat, lane * 4 + 2, f32);
  float c3 = acc.w + ldf(b_gat, lane * 4 + 3, f32);
  c0 = c0 > 0.f ? c0 : expm1f(c0);
  c1 = c1 > 0.f ? c1 : expm1f(c1);
  c2 = c2 > 0.f ? c2 : expm1f(c2);
  c3 = c3 > 0.f ? c3 : expm1f(c3);
  float agg = 0.25f * (c0 + c1 + c2 + c3);

  // GraphCON update (DT=1, Ks=omega=zeta=SP1)
  size_t idx = (size_t)d * NHID + lane;
  float xv = X[idx], yv = Y[idx];
  float yn = yv + (SP1 * agg - 2.f * SP1 * SP1 * yv - SP1 * SP1 * xv);
  float xn = xv + yn;

  // rms_norm both
  float msx = wsum(xn * xn) * (1.f / 64.f);
  xn = xn * rsqrtf(msx + EPSV);
  float msy = wsum(yn * yn) * (1.f / 64.f);
  yn = yn * rsqrtf(msy + EPSV);
  X[idx] = xn;
  Y[idx] = yn;
}

// ---------------- decoder: out = X @ W_dec + b_dec (fp32 output!) ----------------
__global__ __launch_bounds__(256) void k_dec(const float* __restrict__ X,
                                             const void* __restrict__ W_dec,
                                             const void* __restrict__ b_dec,
                                             const int* __restrict__ flag,
                                             float* __restrict__ out) {
  __shared__ float Wl[NHID * NCLASS];
  __shared__ float bl[NCLASS];
  int f32 = flag[1];
  int tid = threadIdx.x;
  for (int i = tid; i < NHID * NCLASS; i += 256) Wl[i] = ldf(W_dec, i, f32);
  if (tid < NCLASS) bl[tid] = ldf(b_dec, tid, f32);
  __syncthreads();
  int g = blockIdx.x * 256 + tid;
  if (g >= N_NODES * NCLASS) return;
  int n = g >> 4, c = g & 15;
  const float* xr = X + (size_t)n * NHID;
  float acc = bl[c];
#pragma unroll
  for (int k = 0; k < NHID; ++k) acc = fmaf(xr[k], Wl[k * NCLASS + c], acc);
  // diagnostic scrub: non-finite anywhere upstream -> recognizable finite signature
  if (!(acc == acc) || fabsf(acc) > 1e6f) acc = 777.0f;
  out[g] = acc;
}

extern "C" void kernel_launch(void* const* d_in, const int* in_sizes, int n_in,
                              void* d_out, int out_size, void* d_ws, size_t ws_size,
                              hipStream_t stream) {
  const void* x       = d_in[0];
  const int*  edge    = (const int*)d_in[1];
  const void* W_enc   = d_in[2];
  const void* b_enc   = d_in[3];
  const void* W_gat   = d_in[4];
  const void* att_src = d_in[5];
  const void* att_dst = d_in[6];
  const void* b_gat   = d_in[7];
  const void* W_dec   = d_in[8];
  const void* b_dec   = d_in[9];

  char* ws = (char*)d_ws;
  size_t off = 0;
  auto alloc = [&](size_t bytes) -> void* {
    if (off + bytes > ws_size) off = 0;  // wrap: aliasing beats foreign-memory corruption
    void* p = ws + off;
    off = (off + bytes + 255) & ~(size_t)255;
    return p;
  };
  // small, integrity-critical arrays first
  int*   flag   = (int*)alloc(256);
  int*   counts = (int*)alloc((size_t)N_NODES * 4);
  int*   rowptr = (int*)alloc((size_t)(N_NODES + 1) * 4);
  int*   cursor = (int*)alloc((size_t)N_NODES * 4);
  int*   ssort  = (int*)alloc((size_t)N_EDGES * 4);
  float* a_src  = (float*)alloc((size_t)N_NODES * HEADS * 4);
  float* a_dst  = (float*)alloc((size_t)N_NODES * HEADS * 4);
  float* X      = (float*)alloc((size_t)N_NODES * NHID * 4);
  float* Y      = (float*)alloc((size_t)N_NODES * NHID * 4);
  unsigned short* hb = (unsigned short*)alloc((size_t)N_NODES * HD * 2);  // bf16 h

  hipMemsetAsync(counts, 0, (size_t)N_NODES * 4, stream);
  k_detect<<<1, 64, 0, stream>>>(edge, (const unsigned*)x, flag);
  k_hist<<<(N_EDGES + 255) / 256, 256, 0, stream>>>(edge, flag, counts);
  k_scan<<<1, 1024, 0, stream>>>(counts, rowptr, cursor);
  k_scatter<<<(N_EDGES + 255) / 256, 256, 0, stream>>>(edge, flag, cursor, ssort);

  k_encoder<<<(N_NODES + 15) / 16, 256, 0, stream>>>(x, W_enc, b_enc, flag, X, Y);
  for (int l = 0; l < 3; ++l) {
    k_proj<<<N_NODES / 32, 256, 0, stream>>>(X, W_gat, att_src, att_dst, flag, hb, a_src, a_dst);
    k_layer<<<N_NODES / 4, 256, 0, stream>>>(hb, a_src, a_dst, rowptr, ssort, b_gat, flag, X, Y);
  }
  k_dec<<<(N_NODES * NCLASS + 255) / 256, 256, 0, stream>>>(X, W_dec, b_dec, flag, (float*)d_out);
}

// Round 5
// 566.622 us; speedup vs baseline: 1.3369x; 1.3369x over previous
//
#include <hip/hip_runtime.h>
#include <hip/hip_bf16.h>

#define DEV static __device__ __forceinline__

constexpr int N_NODES = 20000;
constexpr int N_EDGES = 320000;
constexpr int NFEAT = 128;
constexpr int NHID = 64;
constexpr int NCLASS = 16;
constexpr int HEADS = 4;
constexpr int HD = HEADS * NHID;   // 256
constexpr float EPSV = 1e-5f;
constexpr float SLOPE = 0.2f;
constexpr float SP1 = 1.3132616875182228f;   // softplus(1.0)

DEV float bf2f(__hip_bfloat16 v) { return __bfloat162float(v); }
DEV float bfbits2f(unsigned short b) { return __uint_as_float(((unsigned)b) << 16); }
DEV float lrelu(float v) { return v > 0.f ? v : SLOPE * v; }
DEV int clampn(int v) { return min(max(v, 0), N_NODES - 1); }

DEV float tof(float v) { return v; }
DEV float tof(__hip_bfloat16 v) { return __bfloat162float(v); }

// flag-selected float-input loader (f32 flag is wave-uniform)
DEV float ldf(const void* p, int i, int f32) {
  return f32 ? ((const float*)p)[i] : bf2f(((const __hip_bfloat16*)p)[i]);
}
DEV int eload(const int* e32, int is64, int idx) {
  if (is64) return (int)(((const long long*)e32)[idx]);
  return e32[idx];
}

DEV float wsum(float v) {
#pragma unroll
  for (int m = 32; m > 0; m >>= 1) v += __shfl_xor(v, m, 64);
  return v;
}
DEV float wmax(float v) {
#pragma unroll
  for (int m = 32; m > 0; m >>= 1) v = fmaxf(v, __shfl_xor(v, m, 64));
  return v;
}

// ---------------- dtype probes ----------------
// flag[0]: edge_index is int64 (high dwords of first 64 elements all zero)
// flag[1]: float inputs are fp32 (low-ushort-of-dword exponent junk detected in x)
__global__ void k_detect(const int* __restrict__ edge, const unsigned* __restrict__ xw,
                         int* __restrict__ flag) {
  int t = threadIdx.x;  // 64 threads
  int v = edge[2 * t + 1];
  unsigned long long nz = __ballot(v != 0);
  int bad = 0;
#pragma unroll
  for (int j = 0; j < 4; ++j) {
    unsigned w = xw[t * 4 + j];
    unsigned lu = w & 0xFFFFu;
    unsigned ex = (lu >> 7) & 0xFFu;
    if (ex >= 0x90u) bad = 1;  // |bf16| >= 2^17: impossible for real x (~N(0,1))
  }
  unsigned long long anybad = __ballot(bad != 0);
  if (t == 0) {
    flag[0] = (nz == 0ULL) ? 1 : 0;
    flag[1] = (anybad != 0ULL) ? 1 : 0;
  }
}

// ---------------- CSR build ----------------
__global__ void k_hist(const int* __restrict__ edge, const int* __restrict__ flag,
                       int* __restrict__ counts) {
  int e = blockIdx.x * blockDim.x + threadIdx.x;
  if (e < N_EDGES) {
    int d = clampn(eload(edge, flag[0], N_EDGES + e));
    atomicAdd(&counts[d], 1);
  }
}

__global__ __launch_bounds__(1024) void k_scan(const int* __restrict__ counts,
                                               int* __restrict__ rowptr,
                                               int* __restrict__ cursor) {
  __shared__ int part[1024];
  int t = threadIdx.x;
  const int CH = (N_NODES + 1023) / 1024;  // 20
  int b = t * CH, e = min(b + CH, N_NODES);
  int s = 0;
  for (int i = b; i < e; ++i) s += counts[i];
  part[t] = s;
  __syncthreads();
  for (int off = 1; off < 1024; off <<= 1) {
    int v = (t >= off) ? part[t - off] : 0;
    __syncthreads();
    part[t] += v;
    __syncthreads();
  }
  int run = (t == 0) ? 0 : part[t - 1];
  for (int i = b; i < e; ++i) {
    rowptr[i] = run;
    cursor[i] = run;
    run += counts[i];
  }
  if (t == 1023) rowptr[N_NODES] = N_EDGES;
}

__global__ void k_scatter(const int* __restrict__ edge, const int* __restrict__ flag,
                          int* __restrict__ cursor, int* __restrict__ ssort) {
  int e = blockIdx.x * blockDim.x + threadIdx.x;
  if (e < N_EDGES) {
    int is64 = flag[0];
    int s = clampn(eload(edge, is64, e));
    int d = clampn(eload(edge, is64, N_EDGES + e));
    int pos = atomicAdd(&cursor[d], 1);
    if (pos >= 0 && pos < N_EDGES) ssort[pos] = s;
  }
}

// ---------------- encoder: Y = relu(x @ W_enc + b_enc); X = Y ----------------
// W column in VGPRs (128 regs), 8-node register blocking, wave-uniform x reads.
__global__ __launch_bounds__(256) void k_encoder(const void* __restrict__ x,
                                                 const void* __restrict__ W_enc,
                                                 const void* __restrict__ b_enc,
                                                 const int* __restrict__ flag,
                                                 float* __restrict__ X, float* __restrict__ Y) {
  int f32 = flag[1];
  int tid = threadIdx.x;
  int col = tid & 63;
  int wv = __builtin_amdgcn_readfirstlane(tid >> 6);  // provably wave-uniform
  float wreg[NFEAT];
#pragma unroll
  for (int k = 0; k < NFEAT; ++k) wreg[k] = ldf(W_enc, k * NHID + col, f32);
  float bias = ldf(b_enc, col, f32);
  const int NPB = 32;  // nodes per block, 8 per wave
  int base = blockIdx.x * NPB + wv * 8;

  float acc[8];
#pragma unroll
  for (int j = 0; j < 8; ++j) acc[j] = 0.f;

  if (f32) {
    const float* xb = (const float*)x + (size_t)base * NFEAT;
#pragma unroll
    for (int k = 0; k < NFEAT; ++k) {
#pragma unroll
      for (int j = 0; j < 8; ++j)
        acc[j] = fmaf(xb[(size_t)j * NFEAT + k], wreg[k], acc[j]);
    }
  } else {
    const __hip_bfloat16* xb = (const __hip_bfloat16*)x + (size_t)base * NFEAT;
#pragma unroll
    for (int k = 0; k < NFEAT; ++k) {
#pragma unroll
      for (int j = 0; j < 8; ++j)
        acc[j] = fmaf(bf2f(xb[(size_t)j * NFEAT + k]), wreg[k], acc[j]);
    }
  }
#pragma unroll
  for (int j = 0; j < 8; ++j) {
    int n = base + j;
    float yv = fmaxf(acc[j] + bias, 0.f);
    Y[(size_t)n * NHID + col] = yv;
    X[(size_t)n * NHID + col] = yv;
  }
}

// ---------------- per-layer projection: h = X @ W_gat (bf16 out), a_src/a_dst ----------------
// W column in VGPRs (64 regs), no LDS, 8-node register blocking, wave-uniform X reads (s_load).
__global__ __launch_bounds__(256) void k_proj(const float* __restrict__ X,
                                              const void* __restrict__ W_gat,
                                              const void* __restrict__ att_src,
                                              const void* __restrict__ att_dst,
                                              const int* __restrict__ flag,
                                              unsigned short* __restrict__ hb,
                                              float* __restrict__ a_src,
                                              float* __restrict__ a_dst) {
  int f32 = flag[1];
  int tid = threadIdx.x;
  int lane = tid & 63;
  int head = tid >> 6;
  float asw = ldf(att_src, tid, f32);
  float adw = ldf(att_dst, tid, f32);
  float wreg[NHID];
#pragma unroll
  for (int k = 0; k < NHID; ++k) wreg[k] = ldf(W_gat, k * HD + tid, f32);

  const int NPB = 32;
  int base = blockIdx.x * NPB;
#pragma unroll 1
  for (int c = 0; c < NPB; c += 8) {
    const float* xb = X + (size_t)(base + c) * NHID;
    float acc[8];
#pragma unroll
    for (int j = 0; j < 8; ++j) acc[j] = 0.f;
#pragma unroll
    for (int k = 0; k < NHID; ++k) {
#pragma unroll
      for (int j = 0; j < 8; ++j)
        acc[j] = fmaf(xb[(size_t)j * NHID + k], wreg[k], acc[j]);
    }
#pragma unroll
    for (int j = 0; j < 8; ++j) {
      int n = base + c + j;
      hb[(size_t)n * HD + tid] =
          (unsigned short)__bfloat16_as_ushort(__float2bfloat16(acc[j]));
      float s1 = wsum(acc[j] * asw);
      float s2 = wsum(acc[j] * adw);
      if (lane == 0) {
        a_src[n * HEADS + head] = s1;
        a_dst[n * HEADS + head] = s2;
      }
    }
  }
}

// ---------------- per-layer: softmax-aggregate + ELU + mean + GraphCON + rms ----------------
__global__ __launch_bounds__(256) void k_layer(const unsigned short* __restrict__ hb,
                                               const float* __restrict__ a_src,
                                               const float* __restrict__ a_dst,
                                               const int* __restrict__ rowptr,
                                               const int* __restrict__ srcs,
                                               const void* __restrict__ b_gat,
                                               const int* __restrict__ flag,
                                               float* __restrict__ X, float* __restrict__ Y) {
  int wave = threadIdx.x >> 6, lane = threadIdx.x & 63;
  int f32 = flag[1];
  int d = blockIdx.x * 4 + wave;
  if (d >= N_NODES) return;
  int beg = rowptr[d];
  int end = rowptr[d + 1];
  beg = min(max(beg, 0), N_EDGES);
  end = min(max(end, beg), N_EDGES);
  int deg = end - beg;
  int tot = deg + 1;  // + self loop
  const float4 adv = *(const float4*)(a_dst + d * 4);

  // phase 1: per-head max over incoming edges (edge-parallel across lanes)
  float mx0 = -1e30f, mx1 = -1e30f, mx2 = -1e30f, mx3 = -1e30f;
  for (int i = lane; i < tot; i += 64) {
    int s = (i < deg) ? clampn(srcs[beg + i]) : d;
    const float4 ar = *(const float4*)(a_src + s * 4);
    mx0 = fmaxf(mx0, lrelu(ar.x + adv.x));
    mx1 = fmaxf(mx1, lrelu(ar.y + adv.y));
    mx2 = fmaxf(mx2, lrelu(ar.z + adv.z));
    mx3 = fmaxf(mx3, lrelu(ar.w + adv.w));
  }
  mx0 = wmax(mx0); mx1 = wmax(mx1); mx2 = wmax(mx2); mx3 = wmax(mx3);

  // phase 2: per-head sum(exp)
  float sm0 = 0.f, sm1 = 0.f, sm2 = 0.f, sm3 = 0.f;
  for (int i = lane; i < tot; i += 64) {
    int s = (i < deg) ? clampn(srcs[beg + i]) : d;
    const float4 ar = *(const float4*)(a_src + s * 4);
    sm0 += __expf(lrelu(ar.x + adv.x) - mx0);
    sm1 += __expf(lrelu(ar.y + adv.y) - mx1);
    sm2 += __expf(lrelu(ar.z + adv.z) - mx2);
    sm3 += __expf(lrelu(ar.w + adv.w) - mx3);
  }
  sm0 = wsum(sm0); sm1 = wsum(sm1); sm2 = wsum(sm2); sm3 = wsum(sm3);
  float inv0 = 1.f / (sm0 + 1e-16f), inv1 = 1.f / (sm1 + 1e-16f);
  float inv2 = 1.f / (sm2 + 1e-16f), inv3 = 1.f / (sm3 + 1e-16f);

  // per-lane head selection (lane l covers conv columns 4l..4l+3, all in head l>>4)
  int hd = lane >> 4;
  float adh = (hd == 0) ? adv.x : (hd == 1) ? adv.y : (hd == 2) ? adv.z : adv.w;
  float mxh = (hd == 0) ? mx0 : (hd == 1) ? mx1 : (hd == 2) ? mx2 : mx3;
  float invh = (hd == 0) ? inv0 : (hd == 1) ? inv1 : (hd == 2) ? inv2 : inv3;

  // phase 3: feature-parallel weighted aggregation (bf16 h)
  float4 acc = make_float4(0.f, 0.f, 0.f, 0.f);
  for (int i = 0; i < tot; ++i) {
    int s = (i < deg) ? clampn(srcs[beg + i]) : d;
    float ev = lrelu(a_src[s * 4 + hd] + adh);
    float alpha = __expf(ev - mxh) * invh;
    const ushort4 hv = *(const ushort4*)(hb + (size_t)s * HD + lane * 4);
    acc.x = fmaf(bfbits2f(hv.x), alpha, acc.x);
    acc.y = fmaf(bfbits2f(hv.y), alpha, acc.y);
    acc.z = fmaf(bfbits2f(hv.z), alpha, acc.z);
    acc.w = fmaf(bfbits2f(hv.w), alpha, acc.w);
  }

  // bias + ELU + mean-over-4 (== reshape(N,64,4).mean(-1) at element `lane`)
  float c0 = acc.x + ldf(b_gat, lane * 4 + 0, f32);
  float c1 = acc.y + ldf(b_gat, lane * 4 + 1, f32);
  float c2 = acc.z + ldf(b_gat, lane * 4 + 2, f32);
  float c3 = acc.w + ldf(b_gat, lane * 4 + 3, f32);
  c0 = c0 > 0.f ? c0 : expm1f(c0);
  c1 = c1 > 0.f ? c1 : expm1f(c1);
  c2 = c2 > 0.f ? c2 : expm1f(c2);
  c3 = c3 > 0.f ? c3 : expm1f(c3);
  float agg = 0.25f * (c0 + c1 + c2 + c3);

  // GraphCON update (DT=1, Ks=omega=zeta=SP1)
  size_t idx = (size_t)d * NHID + lane;
  float xv = X[idx], yv = Y[idx];
  float yn = yv + (SP1 * agg - 2.f * SP1 * SP1 * yv - SP1 * SP1 * xv);
  float xn = xv + yn;

  // rms_norm both
  float msx = wsum(xn * xn) * (1.f / 64.f);
  xn = xn * rsqrtf(msx + EPSV);
  float msy = wsum(yn * yn) * (1.f / 64.f);
  yn = yn * rsqrtf(msy + EPSV);
  X[idx] = xn;
  Y[idx] = yn;
}

// ---------------- decoder: out = X @ W_dec + b_dec (fp32 output) ----------------
__global__ __launch_bounds__(256) void k_dec(const float* __restrict__ X,
                                             const void* __restrict__ W_dec,
                                             const void* __restrict__ b_dec,
                                             const int* __restrict__ flag,
                                             float* __restrict__ out) {
  __shared__ float Wl[NHID * NCLASS];
  __shared__ float bl[NCLASS];
  int f32 = flag[1];
  int tid = threadIdx.x;
  for (int i = tid; i < NHID * NCLASS; i += 256) Wl[i] = ldf(W_dec, i, f32);
  if (tid < NCLASS) bl[tid] = ldf(b_dec, tid, f32);
  __syncthreads();
  int g = blockIdx.x * 256 + tid;
  if (g >= N_NODES * NCLASS) return;
  int n = g >> 4, c = g & 15;
  const float* xr = X + (size_t)n * NHID;
  float acc = bl[c];
#pragma unroll
  for (int k = 0; k < NHID; ++k) acc = fmaf(xr[k], Wl[k * NCLASS + c], acc);
  // diagnostic scrub: non-finite anywhere upstream -> recognizable finite signature
  if (!(acc == acc) || fabsf(acc) > 1e6f) acc = 777.0f;
  out[g] = acc;
}

extern "C" void kernel_launch(void* const* d_in, const int* in_sizes, int n_in,
                              void* d_out, int out_size, void* d_ws, size_t ws_size,
                              hipStream_t stream) {
  const void* x       = d_in[0];
  const int*  edge    = (const int*)d_in[1];
  const void* W_enc   = d_in[2];
  const void* b_enc   = d_in[3];
  const void* W_gat   = d_in[4];
  const void* att_src = d_in[5];
  const void* att_dst = d_in[6];
  const void* b_gat   = d_in[7];
  const void* W_dec   = d_in[8];
  const void* b_dec   = d_in[9];

  char* ws = (char*)d_ws;
  size_t off = 0;
  auto alloc = [&](size_t bytes) -> void* {
    if (off + bytes > ws_size) off = 0;  // wrap: aliasing beats foreign-memory corruption
    void* p = ws + off;
    off = (off + bytes + 255) & ~(size_t)255;
    return p;
  };
  // small, integrity-critical arrays first
  int*   flag   = (int*)alloc(256);
  int*   counts = (int*)alloc((size_t)N_NODES * 4);
  int*   rowptr = (int*)alloc((size_t)(N_NODES + 1) * 4);
  int*   cursor = (int*)alloc((size_t)N_NODES * 4);
  int*   ssort  = (int*)alloc((size_t)N_EDGES * 4);
  float* a_src  = (float*)alloc((size_t)N_NODES * HEADS * 4);
  float* a_dst  = (float*)alloc((size_t)N_NODES * HEADS * 4);
  float* X      = (float*)alloc((size_t)N_NODES * NHID * 4);
  float* Y      = (float*)alloc((size_t)N_NODES * NHID * 4);
  unsigned short* hb = (unsigned short*)alloc((size_t)N_NODES * HD * 2);  // bf16 h

  hipMemsetAsync(counts, 0, (size_t)N_NODES * 4, stream);
  k_detect<<<1, 64, 0, stream>>>(edge, (const unsigned*)x, flag);
  k_hist<<<(N_EDGES + 255) / 256, 256, 0, stream>>>(edge, flag, counts);
  k_scan<<<1, 1024, 0, stream>>>(counts, rowptr, cursor);
  k_scatter<<<(N_EDGES + 255) / 256, 256, 0, stream>>>(edge, flag, cursor, ssort);

  k_encoder<<<N_NODES / 32, 256, 0, stream>>>(x, W_enc, b_enc, flag, X, Y);
  for (int l = 0; l < 3; ++l) {
    k_proj<<<N_NODES / 32, 256, 0, stream>>>(X, W_gat, att_src, att_dst, flag, hb, a_src, a_dst);
    k_layer<<<N_NODES / 4, 256, 0, stream>>>(hb, a_src, a_dst, rowptr, ssort, b_gat, flag, X, Y);
  }
  k_dec<<<(N_NODES * NCLASS + 255) / 256, 256, 0, stream>>>(X, W_dec, b_dec, flag, (float*)d_out);
}

// Round 6
// 444.301 us; speedup vs baseline: 1.7049x; 1.2753x over previous
//
#include <hip/hip_runtime.h>
#include <hip/hip_bf16.h>

#define DEV static __device__ __forceinline__

constexpr int N_NODES = 20000;
constexpr int N_EDGES = 320000;
constexpr int NFEAT = 128;
constexpr int NHID = 64;
constexpr int NCLASS = 16;
constexpr int HEADS = 4;
constexpr int HD = HEADS * NHID;   // 256
constexpr float EPSV = 1e-5f;
constexpr float SLOPE = 0.2f;
constexpr float SP1 = 1.3132616875182228f;   // softplus(1.0)

typedef __attribute__((ext_vector_type(8))) short short8;
typedef __attribute__((ext_vector_type(4))) float float4v;

DEV float bf2f(__hip_bfloat16 v) { return __bfloat162float(v); }
DEV float bfbits2f(unsigned short b) { return __uint_as_float(((unsigned)b) << 16); }
DEV short f2bfbits(float v) { return (short)__bfloat16_as_ushort(__float2bfloat16(v)); }
DEV float lrelu(float v) { return v > 0.f ? v : SLOPE * v; }
DEV int clampn(int v) { return min(max(v, 0), N_NODES - 1); }

// flag-selected float-input loader (f32 flag is wave-uniform)
DEV float ldf(const void* p, int i, int f32) {
  return f32 ? ((const float*)p)[i] : bf2f(((const __hip_bfloat16*)p)[i]);
}
DEV int eload(const int* e32, int is64, int idx) {
  if (is64) return (int)(((const long long*)e32)[idx]);
  return e32[idx];
}

DEV float wsum(float v) {
#pragma unroll
  for (int m = 32; m > 0; m >>= 1) v += __shfl_xor(v, m, 64);
  return v;
}
DEV float wmax(float v) {
#pragma unroll
  for (int m = 32; m > 0; m >>= 1) v = fmaxf(v, __shfl_xor(v, m, 64));
  return v;
}
// reduce across the 16 lanes of a quad (lanes differing in bits 0..3)
DEV float qsum(float v) {
#pragma unroll
  for (int m = 1; m < 16; m <<= 1) v += __shfl_xor(v, m, 64);
  return v;
}

// ---------------- dtype probes ----------------
__global__ void k_detect(const int* __restrict__ edge, const unsigned* __restrict__ xw,
                         int* __restrict__ flag) {
  int t = threadIdx.x;  // 64 threads
  int v = edge[2 * t + 1];
  unsigned long long nz = __ballot(v != 0);
  int bad = 0;
#pragma unroll
  for (int j = 0; j < 4; ++j) {
    unsigned w = xw[t * 4 + j];
    unsigned lu = w & 0xFFFFu;
    unsigned ex = (lu >> 7) & 0xFFu;
    if (ex >= 0x90u) bad = 1;  // |bf16| >= 2^17: impossible for real x (~N(0,1))
  }
  unsigned long long anybad = __ballot(bad != 0);
  if (t == 0) {
    flag[0] = (nz == 0ULL) ? 1 : 0;
    flag[1] = (anybad != 0ULL) ? 1 : 0;
  }
}

// ---------------- CSR build ----------------
__global__ void k_hist(const int* __restrict__ edge, const int* __restrict__ flag,
                       int* __restrict__ counts) {
  int e = blockIdx.x * blockDim.x + threadIdx.x;
  if (e < N_EDGES) {
    int d = clampn(eload(edge, flag[0], N_EDGES + e));
    atomicAdd(&counts[d], 1);
  }
}

__global__ __launch_bounds__(1024) void k_scan(const int* __restrict__ counts,
                                               int* __restrict__ rowptr,
                                               int* __restrict__ cursor) {
  __shared__ int part[1024];
  int t = threadIdx.x;
  const int CH = (N_NODES + 1023) / 1024;  // 20
  int b = t * CH, e = min(b + CH, N_NODES);
  int s = 0;
  for (int i = b; i < e; ++i) s += counts[i];
  part[t] = s;
  __syncthreads();
  for (int off = 1; off < 1024; off <<= 1) {
    int v = (t >= off) ? part[t - off] : 0;
    __syncthreads();
    part[t] += v;
    __syncthreads();
  }
  int run = (t == 0) ? 0 : part[t - 1];
  for (int i = b; i < e; ++i) {
    rowptr[i] = run;
    cursor[i] = run;
    run += counts[i];
  }
  if (t == 1023) rowptr[N_NODES] = N_EDGES;
}

__global__ void k_scatter(const int* __restrict__ edge, const int* __restrict__ flag,
                          int* __restrict__ cursor, int* __restrict__ ssort) {
  int e = blockIdx.x * blockDim.x + threadIdx.x;
  if (e < N_EDGES) {
    int is64 = flag[0];
    int s = clampn(eload(edge, is64, e));
    int d = clampn(eload(edge, is64, N_EDGES + e));
    int pos = atomicAdd(&cursor[d], 1);
    if (pos >= 0 && pos < N_EDGES) ssort[pos] = s;
  }
}

// ---------------- encoder (MFMA): Y = relu(x @ W_enc + b_enc); X = Y ----------------
// Block = 16-node M-tile; wave w owns col-tile cols 16w..16w+15. K=128 in 4 steps.
__global__ __launch_bounds__(256) void k_encoder(const void* __restrict__ x,
                                                 const void* __restrict__ W_enc,
                                                 const void* __restrict__ b_enc,
                                                 const int* __restrict__ flag,
                                                 float* __restrict__ X, float* __restrict__ Y) {
  int f32 = flag[1];
  int tid = threadIdx.x;
  int wv = tid >> 6, lane = tid & 63;
  int quad = lane >> 4, m16 = lane & 15;
  int n0 = blockIdx.x * 16;
  int c0 = wv * 16;

  // B frags: W_enc[k][c0+m16], k = ks*32 + quad*8 + j
  short8 bfrag[4];
#pragma unroll
  for (int ks = 0; ks < 4; ++ks)
#pragma unroll
    for (int j = 0; j < 8; ++j)
      bfrag[ks][j] = f2bfbits(ldf(W_enc, (ks * 32 + quad * 8 + j) * NHID + c0 + m16, f32));

  // A frags: x[n0+m16][ks*32 + quad*8 + j]
  float4v acc = {0.f, 0.f, 0.f, 0.f};
#pragma unroll
  for (int ks = 0; ks < 4; ++ks) {
    short8 afrag;
#pragma unroll
    for (int j = 0; j < 8; ++j)
      afrag[j] = f2bfbits(ldf(x, (size_t)(n0 + m16) * NFEAT + ks * 32 + quad * 8 + j, f32));
    acc = __builtin_amdgcn_mfma_f32_16x16x32_bf16(afrag, bfrag[ks], acc, 0, 0, 0);
  }

  float bias = ldf(b_enc, c0 + m16, f32);
#pragma unroll
  for (int r = 0; r < 4; ++r) {
    int n = n0 + quad * 4 + r;            // C/D: row = quad*4 + reg
    float yv = fmaxf(acc[r] + bias, 0.f); //      col = m16
    size_t idx = (size_t)n * NHID + c0 + m16;
    X[idx] = yv;
    Y[idx] = yv;
  }
}

// ---------------- per-layer projection (MFMA): h = X @ W_gat (bf16), a_src/a_dst ----------------
// Block = 16-node M-tile; wave w owns head w (cols 64w..64w+63 = 4 col-tiles). K=64 in 2 steps.
__global__ __launch_bounds__(256) void k_proj(const float* __restrict__ X,
                                              const void* __restrict__ W_gat,
                                              const void* __restrict__ att_src,
                                              const void* __restrict__ att_dst,
                                              const int* __restrict__ flag,
                                              unsigned short* __restrict__ hb,
                                              float* __restrict__ a_src,
                                              float* __restrict__ a_dst) {
  int f32 = flag[1];
  int tid = threadIdx.x;
  int wv = tid >> 6, lane = tid & 63;
  int quad = lane >> 4, m16 = lane & 15;
  int n0 = blockIdx.x * 16;

  // B frags: W_gat[k][col], col = wv*64 + t*16 + m16, k = ks*32 + quad*8 + j
  short8 bfrag[4][2];
#pragma unroll
  for (int t = 0; t < 4; ++t)
#pragma unroll
    for (int ks = 0; ks < 2; ++ks)
#pragma unroll
      for (int j = 0; j < 8; ++j)
        bfrag[t][ks][j] =
            f2bfbits(ldf(W_gat, (ks * 32 + quad * 8 + j) * HD + wv * 64 + t * 16 + m16, f32));

  // A frags: X[n0+m16][ks*32 + quad*8 + j]  (fp32 -> bf16)
  short8 afrag[2];
#pragma unroll
  for (int ks = 0; ks < 2; ++ks)
#pragma unroll
    for (int j = 0; j < 8; ++j)
      afrag[ks][j] = f2bfbits(X[(size_t)(n0 + m16) * NHID + ks * 32 + quad * 8 + j]);

  float4v acc[4];
#pragma unroll
  for (int t = 0; t < 4; ++t) {
    acc[t] = (float4v){0.f, 0.f, 0.f, 0.f};
#pragma unroll
    for (int ks = 0; ks < 2; ++ks)
      acc[t] = __builtin_amdgcn_mfma_f32_16x16x32_bf16(afrag[ks], bfrag[t][ks], acc[t], 0, 0, 0);
  }

  // h store + per-head attention logits. att flat index == global col index.
  float avs[4], avd[4];
#pragma unroll
  for (int t = 0; t < 4; ++t) {
    avs[t] = ldf(att_src, wv * 64 + t * 16 + m16, f32);
    avd[t] = ldf(att_dst, wv * 64 + t * 16 + m16, f32);
  }
  float ps[4], pd[4];
#pragma unroll
  for (int r = 0; r < 4; ++r) { ps[r] = 0.f; pd[r] = 0.f; }
#pragma unroll
  for (int t = 0; t < 4; ++t) {
#pragma unroll
    for (int r = 0; r < 4; ++r) {
      int n = n0 + quad * 4 + r;
      hb[(size_t)n * HD + wv * 64 + t * 16 + m16] = (unsigned short)f2bfbits(acc[t][r]);
      ps[r] = fmaf(acc[t][r], avs[t], ps[r]);
      pd[r] = fmaf(acc[t][r], avd[t], pd[r]);
    }
  }
#pragma unroll
  for (int r = 0; r < 4; ++r) {
    float s = qsum(ps[r]);   // sums the 16 lanes of this quad -> all 64 cols of head wv
    float dq = qsum(pd[r]);
    if (m16 == 0) {
      int n = n0 + quad * 4 + r;
      a_src[n * HEADS + wv] = s;
      a_dst[n * HEADS + wv] = dq;
    }
  }
}

// ---------------- per-layer: softmax-aggregate + ELU + mean + GraphCON + rms ----------------
__global__ __launch_bounds__(256) void k_layer(const unsigned short* __restrict__ hb,
                                               const float* __restrict__ a_src,
                                               const float* __restrict__ a_dst,
                                               const int* __restrict__ rowptr,
                                               const int* __restrict__ srcs,
                                               const void* __restrict__ b_gat,
                                               const int* __restrict__ flag,
                                               float* __restrict__ X, float* __restrict__ Y) {
  int wave = threadIdx.x >> 6, lane = threadIdx.x & 63;
  int f32 = flag[1];
  int d = blockIdx.x * 4 + wave;
  if (d >= N_NODES) return;
  int beg = rowptr[d];
  int end = rowptr[d + 1];
  beg = min(max(beg, 0), N_EDGES);
  end = min(max(end, beg), N_EDGES);
  int deg = end - beg;
  int tot = deg + 1;  // + self loop
  const float4 adv = *(const float4*)(a_dst + d * 4);

  // phase 1: per-head max over incoming edges (edge-parallel across lanes)
  float mx0 = -1e30f, mx1 = -1e30f, mx2 = -1e30f, mx3 = -1e30f;
  for (int i = lane; i < tot; i += 64) {
    int s = (i < deg) ? clampn(srcs[beg + i]) : d;
    const float4 ar = *(const float4*)(a_src + s * 4);
    mx0 = fmaxf(mx0, lrelu(ar.x + adv.x));
    mx1 = fmaxf(mx1, lrelu(ar.y + adv.y));
    mx2 = fmaxf(mx2, lrelu(ar.z + adv.z));
    mx3 = fmaxf(mx3, lrelu(ar.w + adv.w));
  }
  mx0 = wmax(mx0); mx1 = wmax(mx1); mx2 = wmax(mx2); mx3 = wmax(mx3);

  // phase 2: per-head sum(exp)
  float sm0 = 0.f, sm1 = 0.f, sm2 = 0.f, sm3 = 0.f;
  for (int i = lane; i < tot; i += 64) {
    int s = (i < deg) ? clampn(srcs[beg + i]) : d;
    const float4 ar = *(const float4*)(a_src + s * 4);
    sm0 += __expf(lrelu(ar.x + adv.x) - mx0);
    sm1 += __expf(lrelu(ar.y + adv.y) - mx1);
    sm2 += __expf(lrelu(ar.z + adv.z) - mx2);
    sm3 += __expf(lrelu(ar.w + adv.w) - mx3);
  }
  sm0 = wsum(sm0); sm1 = wsum(sm1); sm2 = wsum(sm2); sm3 = wsum(sm3);
  float inv0 = 1.f / (sm0 + 1e-16f), inv1 = 1.f / (sm1 + 1e-16f);
  float inv2 = 1.f / (sm2 + 1e-16f), inv3 = 1.f / (sm3 + 1e-16f);

  // per-lane head selection (lane l covers conv columns 4l..4l+3, all in head l>>4)
  int hd = lane >> 4;
  float adh = (hd == 0) ? adv.x : (hd == 1) ? adv.y : (hd == 2) ? adv.z : adv.w;
  float mxh = (hd == 0) ? mx0 : (hd == 1) ? mx1 : (hd == 2) ? mx2 : mx3;
  float invh = (hd == 0) ? inv0 : (hd == 1) ? inv1 : (hd == 2) ? inv2 : inv3;

  // phase 3: feature-parallel weighted aggregation (bf16 h)
  float4 acc = make_float4(0.f, 0.f, 0.f, 0.f);
  for (int i = 0; i < tot; ++i) {
    int s = (i < deg) ? clampn(srcs[beg + i]) : d;
    float ev = lrelu(a_src[s * 4 + hd] + adh);
    float alpha = __expf(ev - mxh) * invh;
    const ushort4 hv = *(const ushort4*)(hb + (size_t)s * HD + lane * 4);
    acc.x = fmaf(bfbits2f(hv.x), alpha, acc.x);
    acc.y = fmaf(bfbits2f(hv.y), alpha, acc.y);
    acc.z = fmaf(bfbits2f(hv.z), alpha, acc.z);
    acc.w = fmaf(bfbits2f(hv.w), alpha, acc.w);
  }

  // bias + ELU + mean-over-4 (== reshape(N,64,4).mean(-1) at element `lane`)
  float c0 = acc.x + ldf(b_gat, lane * 4 + 0, f32);
  float c1 = acc.y + ldf(b_gat, lane * 4 + 1, f32);
  float c2 = acc.z + ldf(b_gat, lane * 4 + 2, f32);
  float c3 = acc.w + ldf(b_gat, lane * 4 + 3, f32);
  c0 = c0 > 0.f ? c0 : expm1f(c0);
  c1 = c1 > 0.f ? c1 : expm1f(c1);
  c2 = c2 > 0.f ? c2 : expm1f(c2);
  c3 = c3 > 0.f ? c3 : expm1f(c3);
  float agg = 0.25f * (c0 + c1 + c2 + c3);

  // GraphCON update (DT=1, Ks=omega=zeta=SP1)
  size_t idx = (size_t)d * NHID + lane;
  float xv = X[idx], yv = Y[idx];
  float yn = yv + (SP1 * agg - 2.f * SP1 * SP1 * yv - SP1 * SP1 * xv);
  float xn = xv + yn;

  // rms_norm both
  float msx = wsum(xn * xn) * (1.f / 64.f);
  xn = xn * rsqrtf(msx + EPSV);
  float msy = wsum(yn * yn) * (1.f / 64.f);
  yn = yn * rsqrtf(msy + EPSV);
  X[idx] = xn;
  Y[idx] = yn;
}

// ---------------- decoder: out = X @ W_dec + b_dec (fp32 output) ----------------
__global__ __launch_bounds__(256) void k_dec(const float* __restrict__ X,
                                             const void* __restrict__ W_dec,
                                             const void* __restrict__ b_dec,
                                             const int* __restrict__ flag,
                                             float* __restrict__ out) {
  __shared__ float Wl[NHID * NCLASS];
  __shared__ float bl[NCLASS];
  int f32 = flag[1];
  int tid = threadIdx.x;
  for (int i = tid; i < NHID * NCLASS; i += 256) Wl[i] = ldf(W_dec, i, f32);
  if (tid < NCLASS) bl[tid] = ldf(b_dec, tid, f32);
  __syncthreads();
  int g = blockIdx.x * 256 + tid;
  if (g >= N_NODES * NCLASS) return;
  int n = g >> 4, c = g & 15;
  const float* xr = X + (size_t)n * NHID;
  float acc = bl[c];
#pragma unroll
  for (int k = 0; k < NHID; ++k) acc = fmaf(xr[k], Wl[k * NCLASS + c], acc);
  if (!(acc == acc) || fabsf(acc) > 1e6f) acc = 777.0f;
  out[g] = acc;
}

extern "C" void kernel_launch(void* const* d_in, const int* in_sizes, int n_in,
                              void* d_out, int out_size, void* d_ws, size_t ws_size,
                              hipStream_t stream) {
  const void* x       = d_in[0];
  const int*  edge    = (const int*)d_in[1];
  const void* W_enc   = d_in[2];
  const void* b_enc   = d_in[3];
  const void* W_gat   = d_in[4];
  const void* att_src = d_in[5];
  const void* att_dst = d_in[6];
  const void* b_gat   = d_in[7];
  const void* W_dec   = d_in[8];
  const void* b_dec   = d_in[9];

  char* ws = (char*)d_ws;
  size_t off = 0;
  auto alloc = [&](size_t bytes) -> void* {
    if (off + bytes > ws_size) off = 0;  // wrap: aliasing beats foreign-memory corruption
    void* p = ws + off;
    off = (off + bytes + 255) & ~(size_t)255;
    return p;
  };
  int*   flag   = (int*)alloc(256);
  int*   counts = (int*)alloc((size_t)N_NODES * 4);
  int*   rowptr = (int*)alloc((size_t)(N_NODES + 1) * 4);
  int*   cursor = (int*)alloc((size_t)N_NODES * 4);
  int*   ssort  = (int*)alloc((size_t)N_EDGES * 4);
  float* a_src  = (float*)alloc((size_t)N_NODES * HEADS * 4);
  float* a_dst  = (float*)alloc((size_t)N_NODES * HEADS * 4);
  float* X      = (float*)alloc((size_t)N_NODES * NHID * 4);
  float* Y      = (float*)alloc((size_t)N_NODES * NHID * 4);
  unsigned short* hb = (unsigned short*)alloc((size_t)N_NODES * HD * 2);  // bf16 h

  hipMemsetAsync(counts, 0, (size_t)N_NODES * 4, stream);
  k_detect<<<1, 64, 0, stream>>>(edge, (const unsigned*)x, flag);
  k_hist<<<(N_EDGES + 255) / 256, 256, 0, stream>>>(edge, flag, counts);
  k_scan<<<1, 1024, 0, stream>>>(counts, rowptr, cursor);
  k_scatter<<<(N_EDGES + 255) / 256, 256, 0, stream>>>(edge, flag, cursor, ssort);

  k_encoder<<<N_NODES / 16, 256, 0, stream>>>(x, W_enc, b_enc, flag, X, Y);
  for (int l = 0; l < 3; ++l) {
    k_proj<<<N_NODES / 16, 256, 0, stream>>>(X, W_gat, att_src, att_dst, flag, hb, a_src, a_dst);
    k_layer<<<N_NODES / 4, 256, 0, stream>>>(hb, a_src, a_dst, rowptr, ssort, b_gat, flag, X, Y);
  }
  k_dec<<<(N_NODES * NCLASS + 255) / 256, 256, 0, stream>>>(X, W_dec, b_dec, flag, (float*)d_out);
}

// Round 7
// 394.212 us; speedup vs baseline: 1.9215x; 1.1271x over previous
//
#include <hip/hip_runtime.h>
#include <hip/hip_bf16.h>

#define DEV static __device__ __forceinline__

constexpr int N_NODES = 20000;
constexpr int N_EDGES = 320000;
constexpr int NFEAT = 128;
constexpr int NHID = 64;
constexpr int NCLASS = 16;
constexpr int HEADS = 4;
constexpr int HD = HEADS * NHID;   // 256
constexpr float EPSV = 1e-5f;
constexpr float SLOPE = 0.2f;
constexpr float SP1 = 1.3132616875182228f;   // softplus(1.0)

typedef __attribute__((ext_vector_type(8))) short short8;
typedef __attribute__((ext_vector_type(4))) float float4v;

DEV float bf2f(__hip_bfloat16 v) { return __bfloat162float(v); }
DEV float bfbits2f(unsigned short b) { return __uint_as_float(((unsigned)b) << 16); }
DEV short f2bfbits(float v) { return (short)__bfloat16_as_ushort(__float2bfloat16(v)); }
DEV float lrelu(float v) { return v > 0.f ? v : SLOPE * v; }
DEV int clampn(int v) { return min(max(v, 0), N_NODES - 1); }

// flag-selected float-input loader (f32 flag is wave-uniform)
DEV float ldf(const void* p, int i, int f32) {
  return f32 ? ((const float*)p)[i] : bf2f(((const __hip_bfloat16*)p)[i]);
}
DEV int eload(const int* e32, int is64, int idx) {
  if (is64) return (int)(((const long long*)e32)[idx]);
  return e32[idx];
}

DEV float wsum(float v) {
#pragma unroll
  for (int m = 32; m > 0; m >>= 1) v += __shfl_xor(v, m, 64);
  return v;
}
// reduce across the 16 lanes of a quad (lanes differing in bits 0..3)
DEV float qsum(float v) {
#pragma unroll
  for (int m = 1; m < 16; m <<= 1) v += __shfl_xor(v, m, 64);
  return v;
}
DEV float hsel(float4 v, int hd) {
  return (hd == 0) ? v.x : (hd == 1) ? v.y : (hd == 2) ? v.z : v.w;
}

// ---------------- dtype probes ----------------
__global__ void k_detect(const int* __restrict__ edge, const unsigned* __restrict__ xw,
                         int* __restrict__ flag) {
  int t = threadIdx.x;  // 64 threads
  int v = edge[2 * t + 1];
  unsigned long long nz = __ballot(v != 0);
  int bad = 0;
#pragma unroll
  for (int j = 0; j < 4; ++j) {
    unsigned w = xw[t * 4 + j];
    unsigned lu = w & 0xFFFFu;
    unsigned ex = (lu >> 7) & 0xFFu;
    if (ex >= 0x90u) bad = 1;  // |bf16| >= 2^17: impossible for real x (~N(0,1))
  }
  unsigned long long anybad = __ballot(bad != 0);
  if (t == 0) {
    flag[0] = (nz == 0ULL) ? 1 : 0;
    flag[1] = (anybad != 0ULL) ? 1 : 0;
  }
}

// ---------------- CSR build ----------------
__global__ void k_hist(const int* __restrict__ edge, const int* __restrict__ flag,
                       int* __restrict__ counts) {
  int e = blockIdx.x * blockDim.x + threadIdx.x;
  if (e < N_EDGES) {
    int d = clampn(eload(edge, flag[0], N_EDGES + e));
    atomicAdd(&counts[d], 1);
  }
}

__global__ __launch_bounds__(1024) void k_scan(const int* __restrict__ counts,
                                               int* __restrict__ rowptr,
                                               int* __restrict__ cursor) {
  __shared__ int part[1024];
  int t = threadIdx.x;
  const int CH = (N_NODES + 1023) / 1024;  // 20
  int b = t * CH, e = min(b + CH, N_NODES);
  int s = 0;
  for (int i = b; i < e; ++i) s += counts[i];
  part[t] = s;
  __syncthreads();
  for (int off = 1; off < 1024; off <<= 1) {
    int v = (t >= off) ? part[t - off] : 0;
    __syncthreads();
    part[t] += v;
    __syncthreads();
  }
  int run = (t == 0) ? 0 : part[t - 1];
  for (int i = b; i < e; ++i) {
    rowptr[i] = run;
    cursor[i] = run;
    run += counts[i];
  }
  if (t == 1023) rowptr[N_NODES] = N_EDGES;
}

__global__ void k_scatter(const int* __restrict__ edge, const int* __restrict__ flag,
                          int* __restrict__ cursor, int* __restrict__ ssort) {
  int e = blockIdx.x * blockDim.x + threadIdx.x;
  if (e < N_EDGES) {
    int is64 = flag[0];
    int s = clampn(eload(edge, is64, e));
    int d = clampn(eload(edge, is64, N_EDGES + e));
    int pos = atomicAdd(&cursor[d], 1);
    if (pos >= 0 && pos < N_EDGES) ssort[pos] = s;
  }
}

// ---------------- encoder (MFMA): Y = relu(x @ W_enc + b_enc); X = Y ----------------
__global__ __launch_bounds__(256) void k_encoder(const void* __restrict__ x,
                                                 const void* __restrict__ W_enc,
                                                 const void* __restrict__ b_enc,
                                                 const int* __restrict__ flag,
                                                 float* __restrict__ X, float* __restrict__ Y) {
  int f32 = flag[1];
  int tid = threadIdx.x;
  int wv = tid >> 6, lane = tid & 63;
  int quad = lane >> 4, m16 = lane & 15;
  int n0 = blockIdx.x * 16;
  int c0 = wv * 16;

  short8 bfrag[4];
#pragma unroll
  for (int ks = 0; ks < 4; ++ks)
#pragma unroll
    for (int j = 0; j < 8; ++j)
      bfrag[ks][j] = f2bfbits(ldf(W_enc, (ks * 32 + quad * 8 + j) * NHID + c0 + m16, f32));

  float4v acc = {0.f, 0.f, 0.f, 0.f};
#pragma unroll
  for (int ks = 0; ks < 4; ++ks) {
    short8 afrag;
#pragma unroll
    for (int j = 0; j < 8; ++j)
      afrag[j] = f2bfbits(ldf(x, (size_t)(n0 + m16) * NFEAT + ks * 32 + quad * 8 + j, f32));
    acc = __builtin_amdgcn_mfma_f32_16x16x32_bf16(afrag, bfrag[ks], acc, 0, 0, 0);
  }

  float bias = ldf(b_enc, c0 + m16, f32);
#pragma unroll
  for (int r = 0; r < 4; ++r) {
    int n = n0 + quad * 4 + r;            // C/D: row = quad*4 + reg
    float yv = fmaxf(acc[r] + bias, 0.f); //      col = m16
    size_t idx = (size_t)n * NHID + c0 + m16;
    X[idx] = yv;
    Y[idx] = yv;
  }
}

// ---------------- per-layer projection (MFMA): h = X @ W_gat (bf16), a_src/a_dst ----------------
__global__ __launch_bounds__(256) void k_proj(const float* __restrict__ X,
                                              const void* __restrict__ W_gat,
                                              const void* __restrict__ att_src,
                                              const void* __restrict__ att_dst,
                                              const int* __restrict__ flag,
                                              unsigned short* __restrict__ hb,
                                              float* __restrict__ a_src,
                                              float* __restrict__ a_dst) {
  int f32 = flag[1];
  int tid = threadIdx.x;
  int wv = tid >> 6, lane = tid & 63;
  int quad = lane >> 4, m16 = lane & 15;
  int n0 = blockIdx.x * 16;

  short8 bfrag[4][2];
#pragma unroll
  for (int t = 0; t < 4; ++t)
#pragma unroll
    for (int ks = 0; ks < 2; ++ks)
#pragma unroll
      for (int j = 0; j < 8; ++j)
        bfrag[t][ks][j] =
            f2bfbits(ldf(W_gat, (ks * 32 + quad * 8 + j) * HD + wv * 64 + t * 16 + m16, f32));

  short8 afrag[2];
#pragma unroll
  for (int ks = 0; ks < 2; ++ks)
#pragma unroll
    for (int j = 0; j < 8; ++j)
      afrag[ks][j] = f2bfbits(X[(size_t)(n0 + m16) * NHID + ks * 32 + quad * 8 + j]);

  float4v acc[4];
#pragma unroll
  for (int t = 0; t < 4; ++t) {
    acc[t] = (float4v){0.f, 0.f, 0.f, 0.f};
#pragma unroll
    for (int ks = 0; ks < 2; ++ks)
      acc[t] = __builtin_amdgcn_mfma_f32_16x16x32_bf16(afrag[ks], bfrag[t][ks], acc[t], 0, 0, 0);
  }

  float avs[4], avd[4];
#pragma unroll
  for (int t = 0; t < 4; ++t) {
    avs[t] = ldf(att_src, wv * 64 + t * 16 + m16, f32);
    avd[t] = ldf(att_dst, wv * 64 + t * 16 + m16, f32);
  }
  float ps[4], pd[4];
#pragma unroll
  for (int r = 0; r < 4; ++r) { ps[r] = 0.f; pd[r] = 0.f; }
#pragma unroll
  for (int t = 0; t < 4; ++t) {
#pragma unroll
    for (int r = 0; r < 4; ++r) {
      int n = n0 + quad * 4 + r;
      hb[(size_t)n * HD + wv * 64 + t * 16 + m16] = (unsigned short)f2bfbits(acc[t][r]);
      ps[r] = fmaf(acc[t][r], avs[t], ps[r]);
      pd[r] = fmaf(acc[t][r], avd[t], pd[r]);
    }
  }
#pragma unroll
  for (int r = 0; r < 4; ++r) {
    float s = qsum(ps[r]);
    float dq = qsum(pd[r]);
    if (m16 == 0) {
      int n = n0 + quad * 4 + r;
      a_src[n * HEADS + wv] = s;
      a_dst[n * HEADS + wv] = dq;
    }
  }
}

// ---------------- per-layer: softmax-aggregate + ELU + mean + GraphCON + rms ----------------
// Restructured: single gather pass computes per-edge exp weights (no max subtraction;
// logits bounded ~|e|<2) into we[] (coalesced), then a lean 4-deep-batched serial pass
// does only the contiguous hb row gathers.
__global__ __launch_bounds__(256) void k_layer(const unsigned short* __restrict__ hb,
                                               const float* __restrict__ a_src,
                                               const float* __restrict__ a_dst,
                                               const int* __restrict__ rowptr,
                                               const int* __restrict__ srcs,
                                               float* __restrict__ we,
                                               const void* __restrict__ b_gat,
                                               const int* __restrict__ flag,
                                               float* __restrict__ X, float* __restrict__ Y) {
  int wave = threadIdx.x >> 6, lane = threadIdx.x & 63;
  int f32 = flag[1];
  int d = blockIdx.x * 4 + wave;
  if (d >= N_NODES) return;
  int beg = rowptr[d];
  int end = rowptr[d + 1];
  beg = min(max(beg, 0), N_EDGES);
  end = min(max(end, beg), N_EDGES);
  int deg = end - beg;
  const float4 adv = *(const float4*)(a_dst + d * 4);

  // phase A: per-edge exp weights + denominator (single scattered pass over a_src)
  float sm0 = 0.f, sm1 = 0.f, sm2 = 0.f, sm3 = 0.f;
  for (int i = lane; i < deg; i += 64) {
    int p = beg + i;
    int s = clampn(srcs[p]);
    const float4 ar = *(const float4*)(a_src + s * 4);
    float w0 = __expf(lrelu(ar.x + adv.x));
    float w1 = __expf(lrelu(ar.y + adv.y));
    float w2 = __expf(lrelu(ar.z + adv.z));
    float w3 = __expf(lrelu(ar.w + adv.w));
    *(float4*)(we + (size_t)p * 4) = make_float4(w0, w1, w2, w3);
    sm0 += w0; sm1 += w1; sm2 += w2; sm3 += w3;
  }
  sm0 = wsum(sm0); sm1 = wsum(sm1); sm2 = wsum(sm2); sm3 = wsum(sm3);
  // self loop (uniform)
  const float4 ars = *(const float4*)(a_src + d * 4);
  float4 wself = make_float4(__expf(lrelu(ars.x + adv.x)), __expf(lrelu(ars.y + adv.y)),
                             __expf(lrelu(ars.z + adv.z)), __expf(lrelu(ars.w + adv.w)));
  sm0 += wself.x; sm1 += wself.y; sm2 += wself.z; sm3 += wself.w;

  int hd = lane >> 4;
  float invh = 1.f / (hsel(make_float4(sm0, sm1, sm2, sm3), hd) + 1e-16f);
  float wsh = hsel(wself, hd);

  // phase B: weighted aggregation; only contiguous hb gathers in the loop, 4 edges in flight
  float4 acc = make_float4(0.f, 0.f, 0.f, 0.f);
  {  // self loop
    float a = wsh * invh;
    const ushort4 hv = *(const ushort4*)(hb + (size_t)d * HD + lane * 4);
    acc.x = fmaf(bfbits2f(hv.x), a, acc.x);
    acc.y = fmaf(bfbits2f(hv.y), a, acc.y);
    acc.z = fmaf(bfbits2f(hv.z), a, acc.z);
    acc.w = fmaf(bfbits2f(hv.w), a, acc.w);
  }
  int p = beg;
  for (; p + 4 <= end; p += 4) {
    int s0 = clampn(srcs[p + 0]), s1 = clampn(srcs[p + 1]);
    int s2 = clampn(srcs[p + 2]), s3 = clampn(srcs[p + 3]);
    float4 w0 = *(const float4*)(we + (size_t)(p + 0) * 4);
    float4 w1 = *(const float4*)(we + (size_t)(p + 1) * 4);
    float4 w2 = *(const float4*)(we + (size_t)(p + 2) * 4);
    float4 w3 = *(const float4*)(we + (size_t)(p + 3) * 4);
    const ushort4 h0 = *(const ushort4*)(hb + (size_t)s0 * HD + lane * 4);
    const ushort4 h1 = *(const ushort4*)(hb + (size_t)s1 * HD + lane * 4);
    const ushort4 h2 = *(const ushort4*)(hb + (size_t)s2 * HD + lane * 4);
    const ushort4 h3 = *(const ushort4*)(hb + (size_t)s3 * HD + lane * 4);
    float a0 = hsel(w0, hd) * invh, a1 = hsel(w1, hd) * invh;
    float a2 = hsel(w2, hd) * invh, a3 = hsel(w3, hd) * invh;
    acc.x = fmaf(bfbits2f(h0.x), a0, acc.x); acc.y = fmaf(bfbits2f(h0.y), a0, acc.y);
    acc.z = fmaf(bfbits2f(h0.z), a0, acc.z); acc.w = fmaf(bfbits2f(h0.w), a0, acc.w);
    acc.x = fmaf(bfbits2f(h1.x), a1, acc.x); acc.y = fmaf(bfbits2f(h1.y), a1, acc.y);
    acc.z = fmaf(bfbits2f(h1.z), a1, acc.z); acc.w = fmaf(bfbits2f(h1.w), a1, acc.w);
    acc.x = fmaf(bfbits2f(h2.x), a2, acc.x); acc.y = fmaf(bfbits2f(h2.y), a2, acc.y);
    acc.z = fmaf(bfbits2f(h2.z), a2, acc.z); acc.w = fmaf(bfbits2f(h2.w), a2, acc.w);
    acc.x = fmaf(bfbits2f(h3.x), a3, acc.x); acc.y = fmaf(bfbits2f(h3.y), a3, acc.y);
    acc.z = fmaf(bfbits2f(h3.z), a3, acc.z); acc.w = fmaf(bfbits2f(h3.w), a3, acc.w);
  }
  for (; p < end; ++p) {
    int s = clampn(srcs[p]);
    float4 w4 = *(const float4*)(we + (size_t)p * 4);
    float a = hsel(w4, hd) * invh;
    const ushort4 hv = *(const ushort4*)(hb + (size_t)s * HD + lane * 4);
    acc.x = fmaf(bfbits2f(hv.x), a, acc.x);
    acc.y = fmaf(bfbits2f(hv.y), a, acc.y);
    acc.z = fmaf(bfbits2f(hv.z), a, acc.z);
    acc.w = fmaf(bfbits2f(hv.w), a, acc.w);
  }

  // bias + ELU + mean-over-4 (== reshape(N,64,4).mean(-1) at element `lane`)
  float c0 = acc.x + ldf(b_gat, lane * 4 + 0, f32);
  float c1 = acc.y + ldf(b_gat, lane * 4 + 1, f32);
  float c2 = acc.z + ldf(b_gat, lane * 4 + 2, f32);
  float c3 = acc.w + ldf(b_gat, lane * 4 + 3, f32);
  c0 = c0 > 0.f ? c0 : expm1f(c0);
  c1 = c1 > 0.f ? c1 : expm1f(c1);
  c2 = c2 > 0.f ? c2 : expm1f(c2);
  c3 = c3 > 0.f ? c3 : expm1f(c3);
  float agg = 0.25f * (c0 + c1 + c2 + c3);

  // GraphCON update (DT=1, Ks=omega=zeta=SP1)
  size_t idx = (size_t)d * NHID + lane;
  float xv = X[idx], yv = Y[idx];
  float yn = yv + (SP1 * agg - 2.f * SP1 * SP1 * yv - SP1 * SP1 * xv);
  float xn = xv + yn;

  // rms_norm both
  float msx = wsum(xn * xn) * (1.f / 64.f);
  xn = xn * rsqrtf(msx + EPSV);
  float msy = wsum(yn * yn) * (1.f / 64.f);
  yn = yn * rsqrtf(msy + EPSV);
  X[idx] = xn;
  Y[idx] = yn;
}

// ---------------- decoder: out = X @ W_dec + b_dec (fp32 output) ----------------
__global__ __launch_bounds__(256) void k_dec(const float* __restrict__ X,
                                             const void* __restrict__ W_dec,
                                             const void* __restrict__ b_dec,
                                             const int* __restrict__ flag,
                                             float* __restrict__ out) {
  __shared__ float Wl[NHID * NCLASS];
  __shared__ float bl[NCLASS];
  int f32 = flag[1];
  int tid = threadIdx.x;
  for (int i = tid; i < NHID * NCLASS; i += 256) Wl[i] = ldf(W_dec, i, f32);
  if (tid < NCLASS) bl[tid] = ldf(b_dec, tid, f32);
  __syncthreads();
  int g = blockIdx.x * 256 + tid;
  if (g >= N_NODES * NCLASS) return;
  int n = g >> 4, c = g & 15;
  const float* xr = X + (size_t)n * NHID;
  float acc = bl[c];
#pragma unroll
  for (int k = 0; k < NHID; ++k) acc = fmaf(xr[k], Wl[k * NCLASS + c], acc);
  if (!(acc == acc) || fabsf(acc) > 1e6f) acc = 777.0f;
  out[g] = acc;
}

extern "C" void kernel_launch(void* const* d_in, const int* in_sizes, int n_in,
                              void* d_out, int out_size, void* d_ws, size_t ws_size,
                              hipStream_t stream) {
  const void* x       = d_in[0];
  const int*  edge    = (const int*)d_in[1];
  const void* W_enc   = d_in[2];
  const void* b_enc   = d_in[3];
  const void* W_gat   = d_in[4];
  const void* att_src = d_in[5];
  const void* att_dst = d_in[6];
  const void* b_gat   = d_in[7];
  const void* W_dec   = d_in[8];
  const void* b_dec   = d_in[9];

  char* ws = (char*)d_ws;
  size_t off = 0;
  auto alloc = [&](size_t bytes) -> void* {
    if (off + bytes > ws_size) off = 0;  // wrap: aliasing beats foreign-memory corruption
    void* p = ws + off;
    off = (off + bytes + 255) & ~(size_t)255;
    return p;
  };
  int*   flag   = (int*)alloc(256);
  int*   counts = (int*)alloc((size_t)N_NODES * 4);
  int*   rowptr = (int*)alloc((size_t)(N_NODES + 1) * 4);
  int*   cursor = (int*)alloc((size_t)N_NODES * 4);
  int*   ssort  = (int*)alloc((size_t)N_EDGES * 4);
  float* a_src  = (float*)alloc((size_t)N_NODES * HEADS * 4);
  float* a_dst  = (float*)alloc((size_t)N_NODES * HEADS * 4);
  float* X      = (float*)alloc((size_t)N_NODES * NHID * 4);
  float* Y      = (float*)alloc((size_t)N_NODES * NHID * 4);
  unsigned short* hb = (unsigned short*)alloc((size_t)N_NODES * HD * 2);  // bf16 h
  float* we     = (float*)alloc((size_t)N_EDGES * HEADS * 4);             // per-edge exp weights

  hipMemsetAsync(counts, 0, (size_t)N_NODES * 4, stream);
  k_detect<<<1, 64, 0, stream>>>(edge, (const unsigned*)x, flag);
  k_hist<<<(N_EDGES + 255) / 256, 256, 0, stream>>>(edge, flag, counts);
  k_scan<<<1, 1024, 0, stream>>>(counts, rowptr, cursor);
  k_scatter<<<(N_EDGES + 255) / 256, 256, 0, stream>>>(edge, flag, cursor, ssort);

  k_encoder<<<N_NODES / 16, 256, 0, stream>>>(x, W_enc, b_enc, flag, X, Y);
  for (int l = 0; l < 3; ++l) {
    k_proj<<<N_NODES / 16, 256, 0, stream>>>(X, W_gat, att_src, att_dst, flag, hb, a_src, a_dst);
    k_layer<<<N_NODES / 4, 256, 0, stream>>>(hb, a_src, a_dst, rowptr, ssort, we, b_gat, flag, X, Y);
  }
  k_dec<<<(N_NODES * NCLASS + 255) / 256, 256, 0, stream>>>(X, W_dec, b_dec, flag, (float*)d_out);
}

// Round 8
// 358.583 us; speedup vs baseline: 2.1125x; 1.0994x over previous
//
#include <hip/hip_runtime.h>
#include <hip/hip_bf16.h>

#define DEV static __device__ __forceinline__

constexpr int N_NODES = 20000;
constexpr int N_EDGES = 320000;
constexpr int NFEAT = 128;
constexpr int NHID = 64;
constexpr int NCLASS = 16;
constexpr int HEADS = 4;
constexpr int HD = HEADS * NHID;   // 256
constexpr float EPSV = 1e-5f;
constexpr float SLOPE = 0.2f;
constexpr float SP1 = 1.3132616875182228f;   // softplus(1.0)

typedef __attribute__((ext_vector_type(8))) short short8;
typedef __attribute__((ext_vector_type(8))) unsigned short ushort8v;
typedef __attribute__((ext_vector_type(4))) float float4v;

DEV float bf2f(__hip_bfloat16 v) { return __bfloat162float(v); }
DEV float bfbits2f(unsigned short b) { return __uint_as_float(((unsigned)b) << 16); }
DEV short f2bfbits(float v) { return (short)__bfloat16_as_ushort(__float2bfloat16(v)); }
DEV float lrelu(float v) { return v > 0.f ? v : SLOPE * v; }
DEV int clampn(int v) { return min(max(v, 0), N_NODES - 1); }

DEV float ldf(const void* p, int i, int f32) {
  return f32 ? ((const float*)p)[i] : bf2f(((const __hip_bfloat16*)p)[i]);
}
DEV int eload(const int* e32, int is64, int idx) {
  if (is64) return (int)(((const long long*)e32)[idx]);
  return e32[idx];
}

DEV float wsum(float v) {
#pragma unroll
  for (int m = 32; m > 0; m >>= 1) v += __shfl_xor(v, m, 64);
  return v;
}
DEV float qsum(float v) {
#pragma unroll
  for (int m = 1; m < 16; m <<= 1) v += __shfl_xor(v, m, 64);
  return v;
}
DEV float hsel(float4 v, int hd) {
  return (hd == 0) ? v.x : (hd == 1) ? v.y : (hd == 2) ? v.z : v.w;
}

// ---------------- dtype probes ----------------
__global__ void k_detect(const int* __restrict__ edge, const unsigned* __restrict__ xw,
                         int* __restrict__ flag) {
  int t = threadIdx.x;  // 64 threads
  int v = edge[2 * t + 1];
  unsigned long long nz = __ballot(v != 0);
  int bad = 0;
#pragma unroll
  for (int j = 0; j < 4; ++j) {
    unsigned w = xw[t * 4 + j];
    unsigned lu = w & 0xFFFFu;
    unsigned ex = (lu >> 7) & 0xFFu;
    if (ex >= 0x90u) bad = 1;
  }
  unsigned long long anybad = __ballot(bad != 0);
  if (t == 0) {
    flag[0] = (nz == 0ULL) ? 1 : 0;
    flag[1] = (anybad != 0ULL) ? 1 : 0;
  }
}

// ---------------- weight pre-pack: fragment-ordered bf16 (runs once) ----------------
__global__ __launch_bounds__(256) void k_pack(const void* __restrict__ W_enc,
                                              const void* __restrict__ W_gat,
                                              const int* __restrict__ flag,
                                              short* __restrict__ packE,
                                              short* __restrict__ packG) {
  int f32 = flag[1];
  int tid = threadIdx.x;
  int wv = tid >> 6, lane = tid & 63;
  int quad = lane >> 4, m16 = lane & 15;
#pragma unroll
  for (int ks = 0; ks < 4; ++ks)
#pragma unroll
    for (int j = 0; j < 8; ++j)
      packE[(ks * 256 + tid) * 8 + j] =
          f2bfbits(ldf(W_enc, (ks * 32 + quad * 8 + j) * NHID + wv * 16 + m16, f32));
#pragma unroll
  for (int t = 0; t < 4; ++t)
#pragma unroll
    for (int ks = 0; ks < 2; ++ks)
#pragma unroll
      for (int j = 0; j < 8; ++j)
        packG[((t * 2 + ks) * 256 + tid) * 8 + j] =
            f2bfbits(ldf(W_gat, (ks * 32 + quad * 8 + j) * HD + wv * 64 + t * 16 + m16, f32));
}

// ---------------- CSR build ----------------
__global__ void k_hist(const int* __restrict__ edge, const int* __restrict__ flag,
                       int* __restrict__ counts) {
  int e = blockIdx.x * blockDim.x + threadIdx.x;
  if (e < N_EDGES) {
    int d = clampn(eload(edge, flag[0], N_EDGES + e));
    atomicAdd(&counts[d], 1);
  }
}

__global__ __launch_bounds__(1024) void k_scan(const int* __restrict__ counts,
                                               int* __restrict__ rowptr,
                                               int* __restrict__ cursor) {
  __shared__ int part[1024];
  int t = threadIdx.x;
  const int CH = (N_NODES + 1023) / 1024;  // 20
  int b = t * CH, e = min(b + CH, N_NODES);
  int s = 0;
  for (int i = b; i < e; ++i) s += counts[i];
  part[t] = s;
  __syncthreads();
  for (int off = 1; off < 1024; off <<= 1) {
    int v = (t >= off) ? part[t - off] : 0;
    __syncthreads();
    part[t] += v;
    __syncthreads();
  }
  int run = (t == 0) ? 0 : part[t - 1];
  for (int i = b; i < e; ++i) {
    rowptr[i] = run;
    cursor[i] = run;
    run += counts[i];
  }
  if (t == 1023) rowptr[N_NODES] = N_EDGES;
}

__global__ void k_scatter(const int* __restrict__ edge, const int* __restrict__ flag,
                          int* __restrict__ cursor, int* __restrict__ ssort) {
  int e = blockIdx.x * blockDim.x + threadIdx.x;
  if (e < N_EDGES) {
    int is64 = flag[0];
    int s = clampn(eload(edge, is64, e));
    int d = clampn(eload(edge, is64, N_EDGES + e));
    int pos = atomicAdd(&cursor[d], 1);
    if (pos >= 0 && pos < N_EDGES) ssort[pos] = s;
  }
}

// ---------------- encoder (MFMA, packed W): Y = relu(x @ W_enc + b_enc); X = Y ----------------
__global__ __launch_bounds__(256) void k_encoder(const void* __restrict__ x,
                                                 const short* __restrict__ packE,
                                                 const void* __restrict__ b_enc,
                                                 const int* __restrict__ flag,
                                                 float* __restrict__ X, float* __restrict__ Y) {
  int f32 = flag[1];
  int tid = threadIdx.x;
  int wv = tid >> 6, lane = tid & 63;
  int quad = lane >> 4, m16 = lane & 15;
  int n0 = blockIdx.x * 16;
  int c0 = wv * 16;

  float4v acc = {0.f, 0.f, 0.f, 0.f};
#pragma unroll
  for (int ks = 0; ks < 4; ++ks) {
    short8 bfrag = *(const short8*)(packE + (ks * 256 + tid) * 8);
    short8 afrag;
    size_t xoff = (size_t)(n0 + m16) * NFEAT + ks * 32 + quad * 8;
    if (f32) {
      float4 f0 = *(const float4*)((const float*)x + xoff);
      float4 f1 = *(const float4*)((const float*)x + xoff + 4);
      afrag[0] = f2bfbits(f0.x); afrag[1] = f2bfbits(f0.y);
      afrag[2] = f2bfbits(f0.z); afrag[3] = f2bfbits(f0.w);
      afrag[4] = f2bfbits(f1.x); afrag[5] = f2bfbits(f1.y);
      afrag[6] = f2bfbits(f1.z); afrag[7] = f2bfbits(f1.w);
    } else {
      afrag = *(const short8*)((const short*)x + xoff);
    }
    acc = __builtin_amdgcn_mfma_f32_16x16x32_bf16(afrag, bfrag, acc, 0, 0, 0);
  }

  float bias = ldf(b_enc, c0 + m16, f32);
#pragma unroll
  for (int r = 0; r < 4; ++r) {
    int n = n0 + quad * 4 + r;
    float yv = fmaxf(acc[r] + bias, 0.f);
    size_t idx = (size_t)n * NHID + c0 + m16;
    X[idx] = yv;
    Y[idx] = yv;
  }
}

// ---------------- per-layer projection (MFMA, packed W): h = X @ W_gat (bf16), a_src/a_dst ----------------
__global__ __launch_bounds__(256) void k_proj(const float* __restrict__ X,
                                              const short* __restrict__ packG,
                                              const void* __restrict__ att_src,
                                              const void* __restrict__ att_dst,
                                              const int* __restrict__ flag,
                                              unsigned short* __restrict__ hb,
                                              float* __restrict__ a_src,
                                              float* __restrict__ a_dst) {
  int f32 = flag[1];
  int tid = threadIdx.x;
  int wv = tid >> 6, lane = tid & 63;
  int quad = lane >> 4, m16 = lane & 15;
  int n0 = blockIdx.x * 16;

  short8 afrag[2];
#pragma unroll
  for (int ks = 0; ks < 2; ++ks) {
    size_t xoff = (size_t)(n0 + m16) * NHID + ks * 32 + quad * 8;
    float4 f0 = *(const float4*)(X + xoff);
    float4 f1 = *(const float4*)(X + xoff + 4);
    afrag[ks][0] = f2bfbits(f0.x); afrag[ks][1] = f2bfbits(f0.y);
    afrag[ks][2] = f2bfbits(f0.z); afrag[ks][3] = f2bfbits(f0.w);
    afrag[ks][4] = f2bfbits(f1.x); afrag[ks][5] = f2bfbits(f1.y);
    afrag[ks][6] = f2bfbits(f1.z); afrag[ks][7] = f2bfbits(f1.w);
  }

  float4v acc[4];
#pragma unroll
  for (int t = 0; t < 4; ++t) {
    acc[t] = (float4v){0.f, 0.f, 0.f, 0.f};
#pragma unroll
    for (int ks = 0; ks < 2; ++ks) {
      short8 bfrag = *(const short8*)(packG + ((t * 2 + ks) * 256 + tid) * 8);
      acc[t] = __builtin_amdgcn_mfma_f32_16x16x32_bf16(afrag[ks], bfrag, acc[t], 0, 0, 0);
    }
  }

  float avs[4], avd[4];
#pragma unroll
  for (int t = 0; t < 4; ++t) {
    avs[t] = ldf(att_src, wv * 64 + t * 16 + m16, f32);
    avd[t] = ldf(att_dst, wv * 64 + t * 16 + m16, f32);
  }
  float ps[4], pd[4];
#pragma unroll
  for (int r = 0; r < 4; ++r) { ps[r] = 0.f; pd[r] = 0.f; }
#pragma unroll
  for (int t = 0; t < 4; ++t) {
#pragma unroll
    for (int r = 0; r < 4; ++r) {
      int n = n0 + quad * 4 + r;
      hb[(size_t)n * HD + wv * 64 + t * 16 + m16] = (unsigned short)f2bfbits(acc[t][r]);
      ps[r] = fmaf(acc[t][r], avs[t], ps[r]);
      pd[r] = fmaf(acc[t][r], avd[t], pd[r]);
    }
  }
#pragma unroll
  for (int r = 0; r < 4; ++r) {
    float s = qsum(ps[r]);
    float dq = qsum(pd[r]);
    if (m16 == 0) {
      int n = n0 + quad * 4 + r;
      a_src[n * HEADS + wv] = s;
      a_dst[n * HEADS + wv] = dq;
    }
  }
}

// ---------------- per-layer: softmax-aggregate + ELU + mean + GraphCON + rms ----------------
// Half-wave per edge: lane covers 8 cols (ushort8 16-B hb loads), serial iterations halved,
// 4 pairs (8 edges) unrolled. Cross-half combine is exact (symmetric operand order).
__global__ __launch_bounds__(256) void k_layer(const unsigned short* __restrict__ hb,
                                               const float* __restrict__ a_src,
                                               const float* __restrict__ a_dst,
                                               const int* __restrict__ rowptr,
                                               const int* __restrict__ srcs,
                                               float* __restrict__ we,
                                               const void* __restrict__ b_gat,
                                               const int* __restrict__ flag,
                                               float* __restrict__ X, float* __restrict__ Y) {
  int wave = threadIdx.x >> 6, lane = threadIdx.x & 63;
  int half = lane >> 5, l32 = lane & 31, head = l32 >> 3;
  int f32 = flag[1];
  int d = blockIdx.x * 4 + wave;
  if (d >= N_NODES) return;
  int beg = rowptr[d];
  int end = rowptr[d + 1];
  beg = min(max(beg, 0), N_EDGES);
  end = min(max(end, beg), N_EDGES);
  int deg = end - beg;
  const float4 adv = *(const float4*)(a_dst + d * 4);

  // phase A: per-edge exp weights + denominator (edge-parallel across all 64 lanes)
  float sm0 = 0.f, sm1 = 0.f, sm2 = 0.f, sm3 = 0.f;
  for (int i = lane; i < deg; i += 64) {
    int p = beg + i;
    int s = clampn(srcs[p]);
    const float4 ar = *(const float4*)(a_src + s * 4);
    float w0 = __expf(lrelu(ar.x + adv.x));
    float w1 = __expf(lrelu(ar.y + adv.y));
    float w2 = __expf(lrelu(ar.z + adv.z));
    float w3 = __expf(lrelu(ar.w + adv.w));
    *(float4*)(we + (size_t)p * 4) = make_float4(w0, w1, w2, w3);
    sm0 += w0; sm1 += w1; sm2 += w2; sm3 += w3;
  }
  sm0 = wsum(sm0); sm1 = wsum(sm1); sm2 = wsum(sm2); sm3 = wsum(sm3);
  const float4 ars = *(const float4*)(a_src + d * 4);
  float4 wself = make_float4(__expf(lrelu(ars.x + adv.x)), __expf(lrelu(ars.y + adv.y)),
                             __expf(lrelu(ars.z + adv.z)), __expf(lrelu(ars.w + adv.w)));
  sm0 += wself.x; sm1 += wself.y; sm2 += wself.z; sm3 += wself.w;

  float invh = 1.f / (hsel(make_float4(sm0, sm1, sm2, sm3), head) + 1e-16f);

  // phase B: lane handles cols l32*8 .. l32*8+7 of edge (p + half)
  float acc[8];
#pragma unroll
  for (int k = 0; k < 8; ++k) acc[k] = 0.f;
  {  // self loop, weighted only in half 0 (keeps halves symmetric for exact combine)
    float a = (half == 0) ? hsel(wself, head) * invh : 0.f;
    ushort8v hv = *(const ushort8v*)(hb + (size_t)d * HD + l32 * 8);
#pragma unroll
    for (int k = 0; k < 8; ++k) acc[k] = fmaf(bfbits2f(hv[k]), a, acc[k]);
  }
  int p = beg;
  for (; p + 8 <= end; p += 8) {
    int q0 = p + half, q1 = p + 2 + half, q2 = p + 4 + half, q3 = p + 6 + half;
    int s0 = clampn(srcs[q0]), s1 = clampn(srcs[q1]);
    int s2 = clampn(srcs[q2]), s3 = clampn(srcs[q3]);
    float a0 = we[(size_t)q0 * 4 + head] * invh;
    float a1 = we[(size_t)q1 * 4 + head] * invh;
    float a2 = we[(size_t)q2 * 4 + head] * invh;
    float a3 = we[(size_t)q3 * 4 + head] * invh;
    ushort8v h0 = *(const ushort8v*)(hb + (size_t)s0 * HD + l32 * 8);
    ushort8v h1 = *(const ushort8v*)(hb + (size_t)s1 * HD + l32 * 8);
    ushort8v h2 = *(const ushort8v*)(hb + (size_t)s2 * HD + l32 * 8);
    ushort8v h3 = *(const ushort8v*)(hb + (size_t)s3 * HD + l32 * 8);
#pragma unroll
    for (int k = 0; k < 8; ++k) {
      acc[k] = fmaf(bfbits2f(h0[k]), a0, acc[k]);
      acc[k] = fmaf(bfbits2f(h1[k]), a1, acc[k]);
      acc[k] = fmaf(bfbits2f(h2[k]), a2, acc[k]);
      acc[k] = fmaf(bfbits2f(h3[k]), a3, acc[k]);
    }
  }
  for (; p < end; p += 2) {
    int q = p + half;
    bool act = q < end;
    int s = clampn(srcs[act ? q : end - 1]);
    float a = act ? we[(size_t)q * 4 + head] * invh : 0.f;
    ushort8v hv = *(const ushort8v*)(hb + (size_t)s * HD + l32 * 8);
#pragma unroll
    for (int k = 0; k < 8; ++k) acc[k] = fmaf(bfbits2f(hv[k]), a, acc[k]);
  }
  // combine halves (both end with bitwise-identical totals)
#pragma unroll
  for (int k = 0; k < 8; ++k) acc[k] += __shfl_xor(acc[k], 32, 64);

  // bias + ELU + mean-over-4: lane owns mean groups 2*l32 and 2*l32+1
  float cg[8];
#pragma unroll
  for (int k = 0; k < 8; ++k) {
    float c = acc[k] + ldf(b_gat, l32 * 8 + k, f32);
    cg[k] = c > 0.f ? c : expm1f(c);
  }
  float agg0 = 0.25f * (cg[0] + cg[1] + cg[2] + cg[3]);
  float agg1 = 0.25f * (cg[4] + cg[5] + cg[6] + cg[7]);

  // GraphCON update for hidden dims m0=2*l32, m1=2*l32+1
  size_t ix = (size_t)d * NHID + l32 * 2;
  float xv0 = X[ix], xv1 = X[ix + 1];
  float yv0 = Y[ix], yv1 = Y[ix + 1];
  float yn0 = yv0 + (SP1 * agg0 - 2.f * SP1 * SP1 * yv0 - SP1 * SP1 * xv0);
  float yn1 = yv1 + (SP1 * agg1 - 2.f * SP1 * SP1 * yv1 - SP1 * SP1 * xv1);
  float xn0 = xv0 + yn0;
  float xn1 = xv1 + yn1;

  // rms_norm (halves duplicated -> divide by 128)
  float msx = wsum(xn0 * xn0 + xn1 * xn1) * (1.f / 128.f);
  float rx = rsqrtf(msx + EPSV);
  float msy = wsum(yn0 * yn0 + yn1 * yn1) * (1.f / 128.f);
  float ry = rsqrtf(msy + EPSV);
  X[ix] = xn0 * rx; X[ix + 1] = xn1 * rx;
  Y[ix] = yn0 * ry; Y[ix + 1] = yn1 * ry;
}

// ---------------- decoder: out = X @ W_dec + b_dec (fp32 output) ----------------
__global__ __launch_bounds__(256) void k_dec(const float* __restrict__ X,
                                             const void* __restrict__ W_dec,
                                             const void* __restrict__ b_dec,
                                             const int* __restrict__ flag,
                                             float* __restrict__ out) {
  __shared__ float Wl[NHID * NCLASS];
  __shared__ float bl[NCLASS];
  int f32 = flag[1];
  int tid = threadIdx.x;
  for (int i = tid; i < NHID * NCLASS; i += 256) Wl[i] = ldf(W_dec, i, f32);
  if (tid < NCLASS) bl[tid] = ldf(b_dec, tid, f32);
  __syncthreads();
  int g = blockIdx.x * 256 + tid;
  if (g >= N_NODES * NCLASS) return;
  int n = g >> 4, c = g & 15;
  const float* xr = X + (size_t)n * NHID;
  float acc = bl[c];
#pragma unroll
  for (int k = 0; k < NHID; ++k) acc = fmaf(xr[k], Wl[k * NCLASS + c], acc);
  if (!(acc == acc) || fabsf(acc) > 1e6f) acc = 777.0f;
  out[g] = acc;
}

extern "C" void kernel_launch(void* const* d_in, const int* in_sizes, int n_in,
                              void* d_out, int out_size, void* d_ws, size_t ws_size,
                              hipStream_t stream) {
  const void* x       = d_in[0];
  const int*  edge    = (const int*)d_in[1];
  const void* W_enc   = d_in[2];
  const void* b_enc   = d_in[3];
  const void* W_gat   = d_in[4];
  const void* att_src = d_in[5];
  const void* att_dst = d_in[6];
  const void* b_gat   = d_in[7];
  const void* W_dec   = d_in[8];
  const void* b_dec   = d_in[9];

  char* ws = (char*)d_ws;
  size_t off = 0;
  auto alloc = [&](size_t bytes) -> void* {
    if (off + bytes > ws_size) off = 0;  // wrap: aliasing beats foreign-memory corruption
    void* p = ws + off;
    off = (off + bytes + 255) & ~(size_t)255;
    return p;
  };
  int*   flag   = (int*)alloc(256);
  int*   counts = (int*)alloc((size_t)N_NODES * 4);
  int*   rowptr = (int*)alloc((size_t)(N_NODES + 1) * 4);
  int*   cursor = (int*)alloc((size_t)N_NODES * 4);
  int*   ssort  = (int*)alloc((size_t)N_EDGES * 4);
  float* a_src  = (float*)alloc((size_t)N_NODES * HEADS * 4);
  float* a_dst  = (float*)alloc((size_t)N_NODES * HEADS * 4);
  float* X      = (float*)alloc((size_t)N_NODES * NHID * 4);
  float* Y      = (float*)alloc((size_t)N_NODES * NHID * 4);
  short* packE  = (short*)alloc((size_t)4 * 256 * 8 * 2);   // 16 KB
  short* packG  = (short*)alloc((size_t)8 * 256 * 8 * 2);   // 32 KB
  unsigned short* hb = (unsigned short*)alloc((size_t)N_NODES * HD * 2);  // bf16 h
  float* we     = (float*)alloc((size_t)N_EDGES * HEADS * 4);             // per-edge exp weights

  hipMemsetAsync(counts, 0, (size_t)N_NODES * 4, stream);
  k_detect<<<1, 64, 0, stream>>>(edge, (const unsigned*)x, flag);
  k_pack<<<1, 256, 0, stream>>>(W_enc, W_gat, flag, packE, packG);
  k_hist<<<(N_EDGES + 255) / 256, 256, 0, stream>>>(edge, flag, counts);
  k_scan<<<1, 1024, 0, stream>>>(counts, rowptr, cursor);
  k_scatter<<<(N_EDGES + 255) / 256, 256, 0, stream>>>(edge, flag, cursor, ssort);

  k_encoder<<<N_NODES / 16, 256, 0, stream>>>(x, packE, b_enc, flag, X, Y);
  for (int l = 0; l < 3; ++l) {
    k_proj<<<N_NODES / 16, 256, 0, stream>>>(X, packG, att_src, att_dst, flag, hb, a_src, a_dst);
    k_layer<<<N_NODES / 4, 256, 0, stream>>>(hb, a_src, a_dst, rowptr, ssort, we, b_gat, flag, X, Y);
  }
  k_dec<<<(N_NODES * NCLASS + 255) / 256, 256, 0, stream>>>(X, W_dec, b_dec, flag, (float*)d_out);
}

// Round 10
// 354.257 us; speedup vs baseline: 2.1383x; 1.0122x over previous
//
#include <hip/hip_runtime.h>
#include <hip/hip_bf16.h>

#define DEV static __device__ __forceinline__

constexpr int N_NODES = 20000;
constexpr int N_EDGES = 320000;
constexpr int NFEAT = 128;
constexpr int NHID = 64;
constexpr int NCLASS = 16;
constexpr int HEADS = 4;
constexpr int HD = HEADS * NHID;   // 256
constexpr float EPSV = 1e-5f;
constexpr float SLOPE = 0.2f;
constexpr float SP1 = 1.3132616875182228f;   // softplus(1.0)

typedef __attribute__((ext_vector_type(8))) short short8;
typedef __attribute__((ext_vector_type(8))) unsigned short ushort8v;
typedef __attribute__((ext_vector_type(4))) float float4v;

DEV float bf2f(__hip_bfloat16 v) { return __bfloat162float(v); }
DEV float bfbits2f(unsigned short b) { return __uint_as_float(((unsigned)b) << 16); }
DEV short f2bfbits(float v) { return (short)__bfloat16_as_ushort(__float2bfloat16(v)); }
DEV float lrelu(float v) { return v > 0.f ? v : SLOPE * v; }
DEV int clampn(int v) { return min(max(v, 0), N_NODES - 1); }

DEV float ldf(const void* p, int i, int f32) {
  return f32 ? ((const float*)p)[i] : bf2f(((const __hip_bfloat16*)p)[i]);
}
DEV int eload(const int* e32, int is64, int idx) {
  if (is64) return (int)(((const long long*)e32)[idx]);
  return e32[idx];
}

DEV float wsum(float v) {
#pragma unroll
  for (int m = 32; m > 0; m >>= 1) v += __shfl_xor(v, m, 64);
  return v;
}
DEV float qsum(float v) {
#pragma unroll
  for (int m = 1; m < 16; m <<= 1) v += __shfl_xor(v, m, 64);
  return v;
}
DEV float hsel(float4 v, int hd) {
  return (hd == 0) ? v.x : (hd == 1) ? v.y : (hd == 2) ? v.z : v.w;
}

// ---------------- fused dtype probe + weight pre-pack (one launch, 256 thr) ----------------
__global__ __launch_bounds__(256) void k_detect_pack(const int* __restrict__ edge,
                                                     const unsigned* __restrict__ xw,
                                                     const void* __restrict__ W_enc,
                                                     const void* __restrict__ W_gat,
                                                     int* __restrict__ flag,
                                                     short* __restrict__ packE,
                                                     short* __restrict__ packG) {
  __shared__ int sflag[2];
  int tid = threadIdx.x;
  if (tid < 64) {
    int v = edge[2 * tid + 1];
    unsigned long long nz = __ballot(v != 0);
    int bad = 0;
#pragma unroll
    for (int j = 0; j < 4; ++j) {
      unsigned w = xw[tid * 4 + j];
      unsigned ex = ((w & 0xFFFFu) >> 7) & 0xFFu;
      if (ex >= 0x90u) bad = 1;  // |bf16| >= 2^17: impossible for real x (~N(0,1))
    }
    unsigned long long anybad = __ballot(bad != 0);
    if (tid == 0) {
      sflag[0] = (nz == 0ULL) ? 1 : 0;
      sflag[1] = (anybad != 0ULL) ? 1 : 0;
      flag[0] = sflag[0];
      flag[1] = sflag[1];
    }
  }
  __syncthreads();
  int f32 = sflag[1];
  int wv = tid >> 6, lane = tid & 63;
  int quad = lane >> 4, m16 = lane & 15;
#pragma unroll
  for (int ks = 0; ks < 4; ++ks)
#pragma unroll
    for (int j = 0; j < 8; ++j)
      packE[(ks * 256 + tid) * 8 + j] =
          f2bfbits(ldf(W_enc, (ks * 32 + quad * 8 + j) * NHID + wv * 16 + m16, f32));
#pragma unroll
  for (int t = 0; t < 4; ++t)
#pragma unroll
    for (int ks = 0; ks < 2; ++ks)
#pragma unroll
      for (int j = 0; j < 8; ++j)
        packG[((t * 2 + ks) * 256 + tid) * 8 + j] =
            f2bfbits(ldf(W_gat, (ks * 32 + quad * 8 + j) * HD + wv * 64 + t * 16 + m16, f32));
}

// ---------------- CSR build ----------------
__global__ void k_hist(const int* __restrict__ edge, const int* __restrict__ flag,
                       int* __restrict__ counts) {
  int e = blockIdx.x * blockDim.x + threadIdx.x;
  if (e < N_EDGES) {
    int d = clampn(eload(edge, flag[0], N_EDGES + e));
    atomicAdd(&counts[d], 1);
  }
}

__global__ __launch_bounds__(1024) void k_scan(const int* __restrict__ counts,
                                               int* __restrict__ rowptr,
                                               int* __restrict__ cursor) {
  __shared__ int part[1024];
  int t = threadIdx.x;
  const int CH = (N_NODES + 1023) / 1024;  // 20
  int b = t * CH, e = min(b + CH, N_NODES);
  int s = 0;
  for (int i = b; i < e; ++i) s += counts[i];
  part[t] = s;
  __syncthreads();
  for (int off = 1; off < 1024; off <<= 1) {
    int v = (t >= off) ? part[t - off] : 0;
    __syncthreads();
    part[t] += v;
    __syncthreads();
  }
  int run = (t == 0) ? 0 : part[t - 1];
  for (int i = b; i < e; ++i) {
    rowptr[i] = run;
    cursor[i] = run;
    run += counts[i];
  }
  if (t == 1023) rowptr[N_NODES] = N_EDGES;
}

__global__ void k_scatter(const int* __restrict__ edge, const int* __restrict__ flag,
                          int* __restrict__ cursor, int* __restrict__ ssort) {
  int e = blockIdx.x * blockDim.x + threadIdx.x;
  if (e < N_EDGES) {
    int is64 = flag[0];
    int s = clampn(eload(edge, is64, e));
    int d = clampn(eload(edge, is64, N_EDGES + e));
    int pos = atomicAdd(&cursor[d], 1);
    if (pos >= 0 && pos < N_EDGES) ssort[pos] = s;
  }
}

// ---------------- encoder (MFMA, packed W): Y = relu(x @ W_enc + b_enc); X = Y ----------------
__global__ __launch_bounds__(256) void k_encoder(const void* __restrict__ x,
                                                 const short* __restrict__ packE,
                                                 const void* __restrict__ b_enc,
                                                 const int* __restrict__ flag,
                                                 float* __restrict__ X, float* __restrict__ Y) {
  int f32 = flag[1];
  int tid = threadIdx.x;
  int wv = tid >> 6, lane = tid & 63;
  int quad = lane >> 4, m16 = lane & 15;
  int n0 = blockIdx.x * 16;
  int c0 = wv * 16;

  float4v acc = {0.f, 0.f, 0.f, 0.f};
#pragma unroll
  for (int ks = 0; ks < 4; ++ks) {
    short8 bfrag = *(const short8*)(packE + (ks * 256 + tid) * 8);
    short8 afrag;
    size_t xoff = (size_t)(n0 + m16) * NFEAT + ks * 32 + quad * 8;
    if (f32) {
      float4 f0 = *(const float4*)((const float*)x + xoff);
      float4 f1 = *(const float4*)((const float*)x + xoff + 4);
      afrag[0] = f2bfbits(f0.x); afrag[1] = f2bfbits(f0.y);
      afrag[2] = f2bfbits(f0.z); afrag[3] = f2bfbits(f0.w);
      afrag[4] = f2bfbits(f1.x); afrag[5] = f2bfbits(f1.y);
      afrag[6] = f2bfbits(f1.z); afrag[7] = f2bfbits(f1.w);
    } else {
      afrag = *(const short8*)((const short*)x + xoff);
    }
    acc = __builtin_amdgcn_mfma_f32_16x16x32_bf16(afrag, bfrag, acc, 0, 0, 0);
  }

  float bias = ldf(b_enc, c0 + m16, f32);
#pragma unroll
  for (int r = 0; r < 4; ++r) {
    int n = n0 + quad * 4 + r;
    float yv = fmaxf(acc[r] + bias, 0.f);
    size_t idx = (size_t)n * NHID + c0 + m16;
    X[idx] = yv;
    Y[idx] = yv;
  }
}

// ---------------- per-layer projection (MFMA, packed W): h = X @ W_gat (bf16), a_src/a_dst ----------------
__global__ __launch_bounds__(256) void k_proj(const float* __restrict__ X,
                                              const short* __restrict__ packG,
                                              const void* __restrict__ att_src,
                                              const void* __restrict__ att_dst,
                                              const int* __restrict__ flag,
                                              unsigned short* __restrict__ hb,
                                              float* __restrict__ a_src,
                                              float* __restrict__ a_dst) {
  int f32 = flag[1];
  int tid = threadIdx.x;
  int wv = tid >> 6, lane = tid & 63;
  int quad = lane >> 4, m16 = lane & 15;
  int n0 = blockIdx.x * 16;

  short8 afrag[2];
#pragma unroll
  for (int ks = 0; ks < 2; ++ks) {
    size_t xoff = (size_t)(n0 + m16) * NHID + ks * 32 + quad * 8;
    float4 f0 = *(const float4*)(X + xoff);
    float4 f1 = *(const float4*)(X + xoff + 4);
    afrag[ks][0] = f2bfbits(f0.x); afrag[ks][1] = f2bfbits(f0.y);
    afrag[ks][2] = f2bfbits(f0.z); afrag[ks][3] = f2bfbits(f0.w);
    afrag[ks][4] = f2bfbits(f1.x); afrag[ks][5] = f2bfbits(f1.y);
    afrag[ks][6] = f2bfbits(f1.z); afrag[ks][7] = f2bfbits(f1.w);
  }

  float4v acc[4];
#pragma unroll
  for (int t = 0; t < 4; ++t) {
    acc[t] = (float4v){0.f, 0.f, 0.f, 0.f};
#pragma unroll
    for (int ks = 0; ks < 2; ++ks) {
      short8 bfrag = *(const short8*)(packG + ((t * 2 + ks) * 256 + tid) * 8);
      acc[t] = __builtin_amdgcn_mfma_f32_16x16x32_bf16(afrag[ks], bfrag, acc[t], 0, 0, 0);
    }
  }

  float avs[4], avd[4];
#pragma unroll
  for (int t = 0; t < 4; ++t) {
    avs[t] = ldf(att_src, wv * 64 + t * 16 + m16, f32);
    avd[t] = ldf(att_dst, wv * 64 + t * 16 + m16, f32);
  }
  float ps[4], pd[4];
#pragma unroll
  for (int r = 0; r < 4; ++r) { ps[r] = 0.f; pd[r] = 0.f; }
#pragma unroll
  for (int t = 0; t < 4; ++t) {
#pragma unroll
    for (int r = 0; r < 4; ++r) {
      int n = n0 + quad * 4 + r;
      hb[(size_t)n * HD + wv * 64 + t * 16 + m16] =
          (unsigned short)f2bfbits(acc[t][r]);
      ps[r] = fmaf(acc[t][r], avs[t], ps[r]);
      pd[r] = fmaf(acc[t][r], avd[t], pd[r]);
    }
  }
#pragma unroll
  for (int r = 0; r < 4; ++r) {
    float s = qsum(ps[r]);
    float dq = qsum(pd[r]);
    if (m16 == 0) {
      int n = n0 + quad * 4 + r;
      a_src[n * HEADS + wv] = s;
      a_dst[n * HEADS + wv] = dq;
    }
  }
}

// ---------------- per-layer: softmax-aggregate + ELU + mean + GraphCON + rms ----------------
// bf16 hb; half-wave per edge, ushort8 (16 B) loads; invh folded out of the per-edge
// loop (applied once post-combine).
__global__ __launch_bounds__(256) void k_layer(const unsigned short* __restrict__ hb,
                                               const float* __restrict__ a_src,
                                               const float* __restrict__ a_dst,
                                               const int* __restrict__ rowptr,
                                               const int* __restrict__ srcs,
                                               float* __restrict__ we,
                                               const void* __restrict__ b_gat,
                                               const int* __restrict__ flag,
                                               float* __restrict__ X, float* __restrict__ Y) {
  int wave = threadIdx.x >> 6, lane = threadIdx.x & 63;
  int half = lane >> 5, l32 = lane & 31, head = l32 >> 3;
  int f32 = flag[1];
  int d = blockIdx.x * 4 + wave;
  if (d >= N_NODES) return;
  int beg = rowptr[d];
  int end = rowptr[d + 1];
  beg = min(max(beg, 0), N_EDGES);
  end = min(max(end, beg), N_EDGES);
  int deg = end - beg;
  const float4 adv = *(const float4*)(a_dst + d * 4);

  // phase A: per-edge exp weights + denominator (edge-parallel across all 64 lanes)
  float sm0 = 0.f, sm1 = 0.f, sm2 = 0.f, sm3 = 0.f;
  for (int i = lane; i < deg; i += 64) {
    int p = beg + i;
    int s = clampn(srcs[p]);
    const float4 ar = *(const float4*)(a_src + s * 4);
    float w0 = __expf(lrelu(ar.x + adv.x));
    float w1 = __expf(lrelu(ar.y + adv.y));
    float w2 = __expf(lrelu(ar.z + adv.z));
    float w3 = __expf(lrelu(ar.w + adv.w));
    *(float4*)(we + (size_t)p * 4) = make_float4(w0, w1, w2, w3);
    sm0 += w0; sm1 += w1; sm2 += w2; sm3 += w3;
  }
  sm0 = wsum(sm0); sm1 = wsum(sm1); sm2 = wsum(sm2); sm3 = wsum(sm3);
  const float4 ars = *(const float4*)(a_src + d * 4);
  float4 wself = make_float4(__expf(lrelu(ars.x + adv.x)), __expf(lrelu(ars.y + adv.y)),
                             __expf(lrelu(ars.z + adv.z)), __expf(lrelu(ars.w + adv.w)));
  sm0 += wself.x; sm1 += wself.y; sm2 += wself.z; sm3 += wself.w;

  float invh = 1.f / (hsel(make_float4(sm0, sm1, sm2, sm3), head) + 1e-16f);

  // phase B: lane handles cols l32*8 .. l32*8+7 of edge (p + half); raw weights (invh folded)
  float acc[8];
#pragma unroll
  for (int k = 0; k < 8; ++k) acc[k] = 0.f;
  {  // self loop, half 0 only (summed in via the cross-half combine)
    float a = (half == 0) ? hsel(wself, head) : 0.f;
    ushort8v hv = *(const ushort8v*)(hb + (size_t)d * HD + l32 * 8);
#pragma unroll
    for (int k = 0; k < 8; ++k) acc[k] = fmaf(bfbits2f(hv[k]), a, acc[k]);
  }
  int p = beg;
  for (; p + 8 <= end; p += 8) {
    int q0 = p + half, q1 = p + 2 + half, q2 = p + 4 + half, q3 = p + 6 + half;
    int s0 = clampn(srcs[q0]), s1 = clampn(srcs[q1]);
    int s2 = clampn(srcs[q2]), s3 = clampn(srcs[q3]);
    float a0 = we[(size_t)q0 * 4 + head];
    float a1 = we[(size_t)q1 * 4 + head];
    float a2 = we[(size_t)q2 * 4 + head];
    float a3 = we[(size_t)q3 * 4 + head];
    ushort8v h0 = *(const ushort8v*)(hb + (size_t)s0 * HD + l32 * 8);
    ushort8v h1 = *(const ushort8v*)(hb + (size_t)s1 * HD + l32 * 8);
    ushort8v h2 = *(const ushort8v*)(hb + (size_t)s2 * HD + l32 * 8);
    ushort8v h3 = *(const ushort8v*)(hb + (size_t)s3 * HD + l32 * 8);
#pragma unroll
    for (int k = 0; k < 8; ++k) {
      acc[k] = fmaf(bfbits2f(h0[k]), a0, acc[k]);
      acc[k] = fmaf(bfbits2f(h1[k]), a1, acc[k]);
      acc[k] = fmaf(bfbits2f(h2[k]), a2, acc[k]);
      acc[k] = fmaf(bfbits2f(h3[k]), a3, acc[k]);
    }
  }
  for (; p < end; p += 2) {
    int q = p + half;
    bool act = q < end;
    int s = clampn(srcs[act ? q : end - 1]);
    float a = act ? we[(size_t)q * 4 + head] : 0.f;
    ushort8v hv = *(const ushort8v*)(hb + (size_t)s * HD + l32 * 8);
#pragma unroll
    for (int k = 0; k < 8; ++k) acc[k] = fmaf(bfbits2f(hv[k]), a, acc[k]);
  }
  // combine halves (each accumulated its own edge subset; sum = total)
#pragma unroll
  for (int k = 0; k < 8; ++k) acc[k] += __shfl_xor(acc[k], 32, 64);

  // normalize + bias + ELU + mean-over-4: lane owns mean groups 2*l32, 2*l32+1
  float cg[8];
#pragma unroll
  for (int k = 0; k < 8; ++k) {
    float c = acc[k] * invh + ldf(b_gat, l32 * 8 + k, f32);
    cg[k] = c > 0.f ? c : expm1f(c);
  }
  float agg0 = 0.25f * (cg[0] + cg[1] + cg[2] + cg[3]);
  float agg1 = 0.25f * (cg[4] + cg[5] + cg[6] + cg[7]);

  // GraphCON update for hidden dims 2*l32, 2*l32+1
  size_t ix = (size_t)d * NHID + l32 * 2;
  float xv0 = X[ix], xv1 = X[ix + 1];
  float yv0 = Y[ix], yv1 = Y[ix + 1];
  float yn0 = yv0 + (SP1 * agg0 - 2.f * SP1 * SP1 * yv0 - SP1 * SP1 * xv0);
  float yn1 = yv1 + (SP1 * agg1 - 2.f * SP1 * SP1 * yv1 - SP1 * SP1 * xv1);
  float xn0 = xv0 + yn0;
  float xn1 = xv1 + yn1;

  // rms_norm (halves duplicated -> divide by 128)
  float msx = wsum(xn0 * xn0 + xn1 * xn1) * (1.f / 128.f);
  float rx = rsqrtf(msx + EPSV);
  float msy = wsum(yn0 * yn0 + yn1 * yn1) * (1.f / 128.f);
  float ry = rsqrtf(msy + EPSV);
  X[ix] = xn0 * rx; X[ix + 1] = xn1 * rx;
  Y[ix] = yn0 * ry; Y[ix + 1] = yn1 * ry;
}

// ---------------- decoder: out = X @ W_dec + b_dec (fp32 output) ----------------
__global__ __launch_bounds__(256) void k_dec(const float* __restrict__ X,
                                             const void* __restrict__ W_dec,
                                             const void* __restrict__ b_dec,
                                             const int* __restrict__ flag,
                                             float* __restrict__ out) {
  __shared__ float Wl[NHID * NCLASS];
  __shared__ float bl[NCLASS];
  int f32 = flag[1];
  int tid = threadIdx.x;
  for (int i = tid; i < NHID * NCLASS; i += 256) Wl[i] = ldf(W_dec, i, f32);
  if (tid < NCLASS) bl[tid] = ldf(b_dec, tid, f32);
  __syncthreads();
  int g = blockIdx.x * 256 + tid;
  if (g >= N_NODES * NCLASS) return;
  int n = g >> 4, c = g & 15;
  const float* xr = X + (size_t)n * NHID;
  float acc = bl[c];
#pragma unroll
  for (int k = 0; k < NHID; ++k) acc = fmaf(xr[k], Wl[k * NCLASS + c], acc);
  if (!(acc == acc) || fabsf(acc) > 1e6f) acc = 777.0f;
  out[g] = acc;
}

extern "C" void kernel_launch(void* const* d_in, const int* in_sizes, int n_in,
                              void* d_out, int out_size, void* d_ws, size_t ws_size,
                              hipStream_t stream) {
  const void* x       = d_in[0];
  const int*  edge    = (const int*)d_in[1];
  const void* W_enc   = d_in[2];
  const void* b_enc   = d_in[3];
  const void* W_gat   = d_in[4];
  const void* att_src = d_in[5];
  const void* att_dst = d_in[6];
  const void* b_gat   = d_in[7];
  const void* W_dec   = d_in[8];
  const void* b_dec   = d_in[9];

  char* ws = (char*)d_ws;
  size_t off = 0;
  auto alloc = [&](size_t bytes) -> void* {
    if (off + bytes > ws_size) off = 0;  // wrap: aliasing beats foreign-memory corruption
    void* p = ws + off;
    off = (off + bytes + 255) & ~(size_t)255;
    return p;
  };
  int*   flag   = (int*)alloc(256);
  int*   counts = (int*)alloc((size_t)N_NODES * 4);
  int*   rowptr = (int*)alloc((size_t)(N_NODES + 1) * 4);
  int*   cursor = (int*)alloc((size_t)N_NODES * 4);
  int*   ssort  = (int*)alloc((size_t)N_EDGES * 4);
  float* a_src  = (float*)alloc((size_t)N_NODES * HEADS * 4);
  float* a_dst  = (float*)alloc((size_t)N_NODES * HEADS * 4);
  float* X      = (float*)alloc((size_t)N_NODES * NHID * 4);
  float* Y      = (float*)alloc((size_t)N_NODES * NHID * 4);
  short* packE  = (short*)alloc((size_t)4 * 256 * 8 * 2);   // 16 KB
  short* packG  = (short*)alloc((size_t)8 * 256 * 8 * 2);   // 32 KB
  unsigned short* hb = (unsigned short*)alloc((size_t)N_NODES * HD * 2);  // bf16 h
  float* we     = (float*)alloc((size_t)N_EDGES * HEADS * 4);             // per-edge exp weights

  hipMemsetAsync(counts, 0, (size_t)N_NODES * 4, stream);
  k_detect_pack<<<1, 256, 0, stream>>>(edge, (const unsigned*)x, W_enc, W_gat, flag, packE, packG);
  k_hist<<<(N_EDGES + 255) / 256, 256, 0, stream>>>(edge, flag, counts);
  k_scan<<<1, 1024, 0, stream>>>(counts, rowptr, cursor);
  k_scatter<<<(N_EDGES + 255) / 256, 256, 0, stream>>>(edge, flag, cursor, ssort);

  k_encoder<<<N_NODES / 16, 256, 0, stream>>>(x, packE, b_enc, flag, X, Y);
  for (int l = 0; l < 3; ++l) {
    k_proj<<<N_NODES / 16, 256, 0, stream>>>(X, packG, att_src, att_dst, flag, hb, a_src, a_dst);
    k_layer<<<N_NODES / 4, 256, 0, stream>>>(hb, a_src, a_dst, rowptr, ssort, we, b_gat, flag, X, Y);
  }
  k_dec<<<(N_NODES * NCLASS + 255) / 256, 256, 0, stream>>>(X, W_dec, b_dec, flag, (float*)d_out);
}

// Round 11
// 344.408 us; speedup vs baseline: 2.1994x; 1.0286x over previous
//
#include <hip/hip_runtime.h>
#include <hip/hip_bf16.h>

#define DEV static __device__ __forceinline__

constexpr int N_NODES = 20000;
constexpr int N_EDGES = 320000;
constexpr int NFEAT = 128;
constexpr int NHID = 64;
constexpr int NCLASS = 16;
constexpr int HEADS = 4;
constexpr int HD = HEADS * NHID;   // 256
constexpr float EPSV = 1e-5f;
constexpr float SLOPE = 0.2f;
constexpr float SP1 = 1.3132616875182228f;   // softplus(1.0)

typedef __attribute__((ext_vector_type(8))) short short8;
typedef __attribute__((ext_vector_type(4))) float float4v;

DEV float bf2f(__hip_bfloat16 v) { return __bfloat162float(v); }
DEV float bfbits2f(unsigned short b) { return __uint_as_float(((unsigned)b) << 16); }
DEV short f2bfbits(float v) { return (short)__bfloat16_as_ushort(__float2bfloat16(v)); }
DEV float lrelu(float v) { return v > 0.f ? v : SLOPE * v; }
DEV int clampn(int v) { return min(max(v, 0), N_NODES - 1); }

DEV float ldf(const void* p, int i, int f32) {
  return f32 ? ((const float*)p)[i] : bf2f(((const __hip_bfloat16*)p)[i]);
}
DEV int eload(const int* e32, int is64, int idx) {
  if (is64) return (int)(((const long long*)e32)[idx]);
  return e32[idx];
}

DEV float wsum(float v) {
#pragma unroll
  for (int m = 32; m > 0; m >>= 1) v += __shfl_xor(v, m, 64);
  return v;
}
DEV float qsum(float v) {
#pragma unroll
  for (int m = 1; m < 16; m <<= 1) v += __shfl_xor(v, m, 64);
  return v;
}
DEV float hsel(float4 v, int hd) {
  return (hd == 0) ? v.x : (hd == 1) ? v.y : (hd == 2) ? v.z : v.w;
}
// accumulate 8 int8 cols (two dwords) with weight a (row scale folded into a)
DEV void acc8_i8(float* acc, int lo, int hi, float a) {
  acc[0] = fmaf((float)(signed char)(lo), a, acc[0]);
  acc[1] = fmaf((float)(signed char)(lo >> 8), a, acc[1]);
  acc[2] = fmaf((float)(signed char)(lo >> 16), a, acc[2]);
  acc[3] = fmaf((float)(lo >> 24), a, acc[3]);
  acc[4] = fmaf((float)(signed char)(hi), a, acc[4]);
  acc[5] = fmaf((float)(signed char)(hi >> 8), a, acc[5]);
  acc[6] = fmaf((float)(signed char)(hi >> 16), a, acc[6]);
  acc[7] = fmaf((float)(hi >> 24), a, acc[7]);
}

// ---------------- fused dtype probe + weight pre-pack (one launch, 256 thr) ----------------
__global__ __launch_bounds__(256) void k_detect_pack(const int* __restrict__ edge,
                                                     const unsigned* __restrict__ xw,
                                                     const void* __restrict__ W_enc,
                                                     const void* __restrict__ W_gat,
                                                     int* __restrict__ flag,
                                                     short* __restrict__ packE,
                                                     short* __restrict__ packG) {
  __shared__ int sflag[2];
  int tid = threadIdx.x;
  if (tid < 64) {
    int v = edge[2 * tid + 1];
    unsigned long long nz = __ballot(v != 0);
    int bad = 0;
#pragma unroll
    for (int j = 0; j < 4; ++j) {
      unsigned w = xw[tid * 4 + j];
      unsigned ex = ((w & 0xFFFFu) >> 7) & 0xFFu;
      if (ex >= 0x90u) bad = 1;  // |bf16| >= 2^17: impossible for real x (~N(0,1))
    }
    unsigned long long anybad = __ballot(bad != 0);
    if (tid == 0) {
      sflag[0] = (nz == 0ULL) ? 1 : 0;
      sflag[1] = (anybad != 0ULL) ? 1 : 0;
      flag[0] = sflag[0];
      flag[1] = sflag[1];
    }
  }
  __syncthreads();
  int f32 = sflag[1];
  int wv = tid >> 6, lane = tid & 63;
  int quad = lane >> 4, m16 = lane & 15;
#pragma unroll
  for (int ks = 0; ks < 4; ++ks)
#pragma unroll
    for (int j = 0; j < 8; ++j)
      packE[(ks * 256 + tid) * 8 + j] =
          f2bfbits(ldf(W_enc, (ks * 32 + quad * 8 + j) * NHID + wv * 16 + m16, f32));
#pragma unroll
  for (int t = 0; t < 4; ++t)
#pragma unroll
    for (int ks = 0; ks < 2; ++ks)
#pragma unroll
      for (int j = 0; j < 8; ++j)
        packG[((t * 2 + ks) * 256 + tid) * 8 + j] =
            f2bfbits(ldf(W_gat, (ks * 32 + quad * 8 + j) * HD + wv * 64 + t * 16 + m16, f32));
}

// ---------------- CSR build ----------------
__global__ void k_hist(const int* __restrict__ edge, const int* __restrict__ flag,
                       int* __restrict__ counts) {
  int e = blockIdx.x * blockDim.x + threadIdx.x;
  if (e < N_EDGES) {
    int d = clampn(eload(edge, flag[0], N_EDGES + e));
    atomicAdd(&counts[d], 1);
  }
}

__global__ __launch_bounds__(1024) void k_scan(const int* __restrict__ counts,
                                               int* __restrict__ rowptr,
                                               int* __restrict__ cursor) {
  __shared__ int part[1024];
  int t = threadIdx.x;
  const int CH = (N_NODES + 1023) / 1024;  // 20
  int b = t * CH, e = min(b + CH, N_NODES);
  int s = 0;
  for (int i = b; i < e; ++i) s += counts[i];
  part[t] = s;
  __syncthreads();
  for (int off = 1; off < 1024; off <<= 1) {
    int v = (t >= off) ? part[t - off] : 0;
    __syncthreads();
    part[t] += v;
    __syncthreads();
  }
  int run = (t == 0) ? 0 : part[t - 1];
  for (int i = b; i < e; ++i) {
    rowptr[i] = run;
    cursor[i] = run;
    run += counts[i];
  }
  if (t == 1023) rowptr[N_NODES] = N_EDGES;
}

__global__ void k_scatter(const int* __restrict__ edge, const int* __restrict__ flag,
                          int* __restrict__ cursor, int* __restrict__ ssort) {
  int e = blockIdx.x * blockDim.x + threadIdx.x;
  if (e < N_EDGES) {
    int is64 = flag[0];
    int s = clampn(eload(edge, is64, e));
    int d = clampn(eload(edge, is64, N_EDGES + e));
    int pos = atomicAdd(&cursor[d], 1);
    if (pos >= 0 && pos < N_EDGES) ssort[pos] = s;
  }
}

// ---------------- encoder (MFMA, packed W): Y = relu(x @ W_enc + b_enc); X = Y ----------------
__global__ __launch_bounds__(256) void k_encoder(const void* __restrict__ x,
                                                 const short* __restrict__ packE,
                                                 const void* __restrict__ b_enc,
                                                 const int* __restrict__ flag,
                                                 float* __restrict__ X, float* __restrict__ Y) {
  int f32 = flag[1];
  int tid = threadIdx.x;
  int wv = tid >> 6, lane = tid & 63;
  int quad = lane >> 4, m16 = lane & 15;
  int n0 = blockIdx.x * 16;
  int c0 = wv * 16;

  float4v acc = {0.f, 0.f, 0.f, 0.f};
#pragma unroll
  for (int ks = 0; ks < 4; ++ks) {
    short8 bfrag = *(const short8*)(packE + (ks * 256 + tid) * 8);
    short8 afrag;
    size_t xoff = (size_t)(n0 + m16) * NFEAT + ks * 32 + quad * 8;
    if (f32) {
      float4 f0 = *(const float4*)((const float*)x + xoff);
      float4 f1 = *(const float4*)((const float*)x + xoff + 4);
      afrag[0] = f2bfbits(f0.x); afrag[1] = f2bfbits(f0.y);
      afrag[2] = f2bfbits(f0.z); afrag[3] = f2bfbits(f0.w);
      afrag[4] = f2bfbits(f1.x); afrag[5] = f2bfbits(f1.y);
      afrag[6] = f2bfbits(f1.z); afrag[7] = f2bfbits(f1.w);
    } else {
      afrag = *(const short8*)((const short*)x + xoff);
    }
    acc = __builtin_amdgcn_mfma_f32_16x16x32_bf16(afrag, bfrag, acc, 0, 0, 0);
  }

  float bias = ldf(b_enc, c0 + m16, f32);
#pragma unroll
  for (int r = 0; r < 4; ++r) {
    int n = n0 + quad * 4 + r;
    float yv = fmaxf(acc[r] + bias, 0.f);
    size_t idx = (size_t)n * NHID + c0 + m16;
    X[idx] = yv;
    Y[idx] = yv;
  }
}

// ---------------- per-layer projection (MFMA): h = X @ W_gat -> int8 row-scaled ----------------
__global__ __launch_bounds__(256) void k_proj(const float* __restrict__ X,
                                              const short* __restrict__ packG,
                                              const void* __restrict__ att_src,
                                              const void* __restrict__ att_dst,
                                              const int* __restrict__ flag,
                                              signed char* __restrict__ hb,
                                              float* __restrict__ hscale,
                                              float* __restrict__ a_src,
                                              float* __restrict__ a_dst) {
  __shared__ float smax[4][16];  // [wave][row-in-tile]
  int f32 = flag[1];
  int tid = threadIdx.x;
  int wv = tid >> 6, lane = tid & 63;
  int quad = lane >> 4, m16 = lane & 15;
  int n0 = blockIdx.x * 16;

  short8 afrag[2];
#pragma unroll
  for (int ks = 0; ks < 2; ++ks) {
    size_t xoff = (size_t)(n0 + m16) * NHID + ks * 32 + quad * 8;
    float4 f0 = *(const float4*)(X + xoff);
    float4 f1 = *(const float4*)(X + xoff + 4);
    afrag[ks][0] = f2bfbits(f0.x); afrag[ks][1] = f2bfbits(f0.y);
    afrag[ks][2] = f2bfbits(f0.z); afrag[ks][3] = f2bfbits(f0.w);
    afrag[ks][4] = f2bfbits(f1.x); afrag[ks][5] = f2bfbits(f1.y);
    afrag[ks][6] = f2bfbits(f1.z); afrag[ks][7] = f2bfbits(f1.w);
  }

  float4v acc[4];
#pragma unroll
  for (int t = 0; t < 4; ++t) {
    acc[t] = (float4v){0.f, 0.f, 0.f, 0.f};
#pragma unroll
    for (int ks = 0; ks < 2; ++ks) {
      short8 bfrag = *(const short8*)(packG + ((t * 2 + ks) * 256 + tid) * 8);
      acc[t] = __builtin_amdgcn_mfma_f32_16x16x32_bf16(afrag[ks], bfrag, acc[t], 0, 0, 0);
    }
  }

  // per-row absmax: reduce over t (local), m16 lanes (shfl), then waves (LDS)
  float amax[4];
#pragma unroll
  for (int r = 0; r < 4; ++r) {
    float m = fmaxf(fmaxf(fabsf(acc[0][r]), fabsf(acc[1][r])),
                    fmaxf(fabsf(acc[2][r]), fabsf(acc[3][r])));
#pragma unroll
    for (int sh = 1; sh < 16; sh <<= 1) m = fmaxf(m, __shfl_xor(m, sh, 64));
    amax[r] = m;
  }
  if (m16 == 0) {
#pragma unroll
    for (int r = 0; r < 4; ++r) smax[wv][quad * 4 + r] = amax[r];
  }
  __syncthreads();
  float inv[4];
#pragma unroll
  for (int r = 0; r < 4; ++r) {
    int row = quad * 4 + r;
    float m = fmaxf(fmaxf(smax[0][row], smax[1][row]), fmaxf(smax[2][row], smax[3][row]));
    inv[r] = (m > 0.f) ? 127.f / m : 0.f;
  }
  if (tid < 16) {
    float m = fmaxf(fmaxf(smax[0][tid], smax[1][tid]), fmaxf(smax[2][tid], smax[3][tid]));
    hscale[n0 + tid] = m * (1.f / 127.f);
  }

  float avs[4], avd[4];
#pragma unroll
  for (int t = 0; t < 4; ++t) {
    avs[t] = ldf(att_src, wv * 64 + t * 16 + m16, f32);
    avd[t] = ldf(att_dst, wv * 64 + t * 16 + m16, f32);
  }
  float ps[4], pd[4];
#pragma unroll
  for (int r = 0; r < 4; ++r) { ps[r] = 0.f; pd[r] = 0.f; }
#pragma unroll
  for (int t = 0; t < 4; ++t) {
#pragma unroll
    for (int r = 0; r < 4; ++r) {
      int n = n0 + quad * 4 + r;
      hb[(size_t)n * HD + wv * 64 + t * 16 + m16] =
          (signed char)__float2int_rn(acc[t][r] * inv[r]);
      ps[r] = fmaf(acc[t][r], avs[t], ps[r]);
      pd[r] = fmaf(acc[t][r], avd[t], pd[r]);
    }
  }
#pragma unroll
  for (int r = 0; r < 4; ++r) {
    float s = qsum(ps[r]);
    float dq = qsum(pd[r]);
    if (m16 == 0) {
      int n = n0 + quad * 4 + r;
      a_src[n * HEADS + wv] = s;
      a_dst[n * HEADS + wv] = dq;
    }
  }
}

// ---------------- per-layer: softmax-aggregate + ELU + mean + GraphCON + rms ----------------
// int8 row-scaled hb (256-B rows): half-wave per edge, uint2 (8 B = 8 cols) loads.
// Row scale folded into we at phase-A time; denominators use unscaled weights.
__global__ __launch_bounds__(256) void k_layer(const signed char* __restrict__ hb,
                                               const float* __restrict__ hscale,
                                               const float* __restrict__ a_src,
                                               const float* __restrict__ a_dst,
                                               const int* __restrict__ rowptr,
                                               const int* __restrict__ srcs,
                                               float* __restrict__ we,
                                               const void* __restrict__ b_gat,
                                               const int* __restrict__ flag,
                                               float* __restrict__ X, float* __restrict__ Y) {
  int wave = threadIdx.x >> 6, lane = threadIdx.x & 63;
  int half = lane >> 5, l32 = lane & 31, head = l32 >> 3;
  int f32 = flag[1];
  int d = blockIdx.x * 4 + wave;
  if (d >= N_NODES) return;
  int beg = rowptr[d];
  int end = rowptr[d + 1];
  beg = min(max(beg, 0), N_EDGES);
  end = min(max(end, beg), N_EDGES);
  int deg = end - beg;
  const float4 adv = *(const float4*)(a_dst + d * 4);

  // phase A: per-edge exp weights (row-scale folded) + denominator (unscaled)
  float sm0 = 0.f, sm1 = 0.f, sm2 = 0.f, sm3 = 0.f;
  for (int i = lane; i < deg; i += 64) {
    int p = beg + i;
    int s = clampn(srcs[p]);
    const float4 ar = *(const float4*)(a_src + s * 4);
    float scl = hscale[s];
    float w0 = __expf(lrelu(ar.x + adv.x));
    float w1 = __expf(lrelu(ar.y + adv.y));
    float w2 = __expf(lrelu(ar.z + adv.z));
    float w3 = __expf(lrelu(ar.w + adv.w));
    *(float4*)(we + (size_t)p * 4) = make_float4(w0 * scl, w1 * scl, w2 * scl, w3 * scl);
    sm0 += w0; sm1 += w1; sm2 += w2; sm3 += w3;
  }
  sm0 = wsum(sm0); sm1 = wsum(sm1); sm2 = wsum(sm2); sm3 = wsum(sm3);
  const float4 ars = *(const float4*)(a_src + d * 4);
  float4 wself = make_float4(__expf(lrelu(ars.x + adv.x)), __expf(lrelu(ars.y + adv.y)),
                             __expf(lrelu(ars.z + adv.z)), __expf(lrelu(ars.w + adv.w)));
  sm0 += wself.x; sm1 += wself.y; sm2 += wself.z; sm3 += wself.w;

  float invh = 1.f / (hsel(make_float4(sm0, sm1, sm2, sm3), head) + 1e-16f);

  // phase B: lane handles cols l32*8 .. l32*8+7 of edge (p + half)
  float acc[8];
#pragma unroll
  for (int k = 0; k < 8; ++k) acc[k] = 0.f;
  {  // self loop, half 0 only (summed in via the cross-half combine)
    float a = (half == 0) ? hsel(wself, head) * hscale[d] : 0.f;
    uint2 hv = *(const uint2*)(hb + (size_t)d * HD + l32 * 8);
    acc8_i8(acc, (int)hv.x, (int)hv.y, a);
  }
  int p = beg;
  for (; p + 8 <= end; p += 8) {
    int q0 = p + half, q1 = p + 2 + half, q2 = p + 4 + half, q3 = p + 6 + half;
    int s0 = clampn(srcs[q0]), s1 = clampn(srcs[q1]);
    int s2 = clampn(srcs[q2]), s3 = clampn(srcs[q3]);
    float a0 = we[(size_t)q0 * 4 + head];
    float a1 = we[(size_t)q1 * 4 + head];
    float a2 = we[(size_t)q2 * 4 + head];
    float a3 = we[(size_t)q3 * 4 + head];
    uint2 h0 = *(const uint2*)(hb + (size_t)s0 * HD + l32 * 8);
    uint2 h1 = *(const uint2*)(hb + (size_t)s1 * HD + l32 * 8);
    uint2 h2 = *(const uint2*)(hb + (size_t)s2 * HD + l32 * 8);
    uint2 h3 = *(const uint2*)(hb + (size_t)s3 * HD + l32 * 8);
    acc8_i8(acc, (int)h0.x, (int)h0.y, a0);
    acc8_i8(acc, (int)h1.x, (int)h1.y, a1);
    acc8_i8(acc, (int)h2.x, (int)h2.y, a2);
    acc8_i8(acc, (int)h3.x, (int)h3.y, a3);
  }
  for (; p < end; p += 2) {
    int q = p + half;
    bool act = q < end;
    int s = clampn(srcs[act ? q : end - 1]);
    float a = act ? we[(size_t)q * 4 + head] : 0.f;
    uint2 hv = *(const uint2*)(hb + (size_t)s * HD + l32 * 8);
    acc8_i8(acc, (int)hv.x, (int)hv.y, a);
  }
  // combine halves (each accumulated its own edge subset; sum = total)
#pragma unroll
  for (int k = 0; k < 8; ++k) acc[k] += __shfl_xor(acc[k], 32, 64);

  // normalize + bias + ELU + mean-over-4: lane owns mean groups 2*l32, 2*l32+1
  float cg[8];
#pragma unroll
  for (int k = 0; k < 8; ++k) {
    float c = acc[k] * invh + ldf(b_gat, l32 * 8 + k, f32);
    cg[k] = c > 0.f ? c : expm1f(c);
  }
  float agg0 = 0.25f * (cg[0] + cg[1] + cg[2] + cg[3]);
  float agg1 = 0.25f * (cg[4] + cg[5] + cg[6] + cg[7]);

  // GraphCON update for hidden dims 2*l32, 2*l32+1
  size_t ix = (size_t)d * NHID + l32 * 2;
  float xv0 = X[ix], xv1 = X[ix + 1];
  float yv0 = Y[ix], yv1 = Y[ix + 1];
  float yn0 = yv0 + (SP1 * agg0 - 2.f * SP1 * SP1 * yv0 - SP1 * SP1 * xv0);
  float yn1 = yv1 + (SP1 * agg1 - 2.f * SP1 * SP1 * yv1 - SP1 * SP1 * xv1);
  float xn0 = xv0 + yn0;
  float xn1 = xv1 + yn1;

  // rms_norm (halves duplicated -> divide by 128)
  float msx = wsum(xn0 * xn0 + xn1 * xn1) * (1.f / 128.f);
  float rx = rsqrtf(msx + EPSV);
  float msy = wsum(yn0 * yn0 + yn1 * yn1) * (1.f / 128.f);
  float ry = rsqrtf(msy + EPSV);
  X[ix] = xn0 * rx; X[ix + 1] = xn1 * rx;
  Y[ix] = yn0 * ry; Y[ix + 1] = yn1 * ry;
}

// ---------------- decoder: out = X @ W_dec + b_dec (fp32 output) ----------------
__global__ __launch_bounds__(256) void k_dec(const float* __restrict__ X,
                                             const void* __restrict__ W_dec,
                                             const void* __restrict__ b_dec,
                                             const int* __restrict__ flag,
                                             float* __restrict__ out) {
  __shared__ float Wl[NHID * NCLASS];
  __shared__ float bl[NCLASS];
  int f32 = flag[1];
  int tid = threadIdx.x;
  for (int i = tid; i < NHID * NCLASS; i += 256) Wl[i] = ldf(W_dec, i, f32);
  if (tid < NCLASS) bl[tid] = ldf(b_dec, tid, f32);
  __syncthreads();
  int g = blockIdx.x * 256 + tid;
  if (g >= N_NODES * NCLASS) return;
  int n = g >> 4, c = g & 15;
  const float* xr = X + (size_t)n * NHID;
  float acc = bl[c];
#pragma unroll
  for (int k = 0; k < NHID; ++k) acc = fmaf(xr[k], Wl[k * NCLASS + c], acc);
  if (!(acc == acc) || fabsf(acc) > 1e6f) acc = 777.0f;
  out[g] = acc;
}

extern "C" void kernel_launch(void* const* d_in, const int* in_sizes, int n_in,
                              void* d_out, int out_size, void* d_ws, size_t ws_size,
                              hipStream_t stream) {
  const void* x       = d_in[0];
  const int*  edge    = (const int*)d_in[1];
  const void* W_enc   = d_in[2];
  const void* b_enc   = d_in[3];
  const void* W_gat   = d_in[4];
  const void* att_src = d_in[5];
  const void* att_dst = d_in[6];
  const void* b_gat   = d_in[7];
  const void* W_dec   = d_in[8];
  const void* b_dec   = d_in[9];

  char* ws = (char*)d_ws;
  size_t off = 0;
  auto alloc = [&](size_t bytes) -> void* {
    if (off + bytes > ws_size) off = 0;  // wrap: aliasing beats foreign-memory corruption
    void* p = ws + off;
    off = (off + bytes + 255) & ~(size_t)255;
    return p;
  };
  int*   flag   = (int*)alloc(256);
  int*   counts = (int*)alloc((size_t)N_NODES * 4);
  int*   rowptr = (int*)alloc((size_t)(N_NODES + 1) * 4);
  int*   cursor = (int*)alloc((size_t)N_NODES * 4);
  int*   ssort  = (int*)alloc((size_t)N_EDGES * 4);
  float* a_src  = (float*)alloc((size_t)N_NODES * HEADS * 4);
  float* a_dst  = (float*)alloc((size_t)N_NODES * HEADS * 4);
  float* X      = (float*)alloc((size_t)N_NODES * NHID * 4);
  float* Y      = (float*)alloc((size_t)N_NODES * NHID * 4);
  float* hscale = (float*)alloc((size_t)N_NODES * 4);
  short* packE  = (short*)alloc((size_t)4 * 256 * 8 * 2);   // 16 KB
  short* packG  = (short*)alloc((size_t)8 * 256 * 8 * 2);   // 32 KB
  signed char* hb = (signed char*)alloc((size_t)N_NODES * HD);  // int8 h (5.12 MB)
  float* we     = (float*)alloc((size_t)N_EDGES * HEADS * 4);   // per-edge scaled exp weights

  hipMemsetAsync(counts, 0, (size_t)N_NODES * 4, stream);
  k_detect_pack<<<1, 256, 0, stream>>>(edge, (const unsigned*)x, W_enc, W_gat, flag, packE, packG);
  k_hist<<<(N_EDGES + 255) / 256, 256, 0, stream>>>(edge, flag, counts);
  k_scan<<<1, 1024, 0, stream>>>(counts, rowptr, cursor);
  k_scatter<<<(N_EDGES + 255) / 256, 256, 0, stream>>>(edge, flag, cursor, ssort);

  k_encoder<<<N_NODES / 16, 256, 0, stream>>>(x, packE, b_enc, flag, X, Y);
  for (int l = 0; l < 3; ++l) {
    k_proj<<<N_NODES / 16, 256, 0, stream>>>(X, packG, att_src, att_dst, flag, hb, hscale, a_src, a_dst);
    k_layer<<<N_NODES / 4, 256, 0, stream>>>(hb, hscale, a_src, a_dst, rowptr, ssort, we, b_gat, flag, X, Y);
  }
  k_dec<<<(N_NODES * NCLASS + 255) / 256, 256, 0, stream>>>(X, W_dec, b_dec, flag, (float*)d_out);
}

// Round 12
// 333.978 us; speedup vs baseline: 2.2681x; 1.0312x over previous
//
#include <hip/hip_runtime.h>
#include <hip/hip_bf16.h>

#define DEV static __device__ __forceinline__

constexpr int N_NODES = 20000;
constexpr int N_EDGES = 320000;
constexpr int NFEAT = 128;
constexpr int NHID = 64;
constexpr int NCLASS = 16;
constexpr int HEADS = 4;
constexpr int HD = HEADS * NHID;   // 256
constexpr float EPSV = 1e-5f;
constexpr float SLOPE = 0.2f;
constexpr float SP1 = 1.3132616875182228f;   // softplus(1.0)

typedef __attribute__((ext_vector_type(8))) short short8;
typedef __attribute__((ext_vector_type(4))) float float4v;

DEV float bf2f(__hip_bfloat16 v) { return __bfloat162float(v); }
DEV short f2bfbits(float v) { return (short)__bfloat16_as_ushort(__float2bfloat16(v)); }
DEV float lrelu(float v) { return v > 0.f ? v : SLOPE * v; }
DEV int clampn(int v) { return min(max(v, 0), N_NODES - 1); }

DEV float ldf(const void* p, int i, int f32) {
  return f32 ? ((const float*)p)[i] : bf2f(((const __hip_bfloat16*)p)[i]);
}
DEV int eload(const int* e32, int is64, int idx) {
  if (is64) return (int)(((const long long*)e32)[idx]);
  return e32[idx];
}

DEV float wsum(float v) {
#pragma unroll
  for (int m = 32; m > 0; m >>= 1) v += __shfl_xor(v, m, 64);
  return v;
}
DEV float qsum(float v) {
#pragma unroll
  for (int m = 1; m < 16; m <<= 1) v += __shfl_xor(v, m, 64);
  return v;
}
// accumulate 8 int8 cols (two dwords) with weight a (row scale folded into a)
DEV void acc8_i8(float* acc, int lo, int hi, float a) {
  acc[0] = fmaf((float)(signed char)(lo), a, acc[0]);
  acc[1] = fmaf((float)(signed char)(lo >> 8), a, acc[1]);
  acc[2] = fmaf((float)(signed char)(lo >> 16), a, acc[2]);
  acc[3] = fmaf((float)(lo >> 24), a, acc[3]);
  acc[4] = fmaf((float)(signed char)(hi), a, acc[4]);
  acc[5] = fmaf((float)(signed char)(hi >> 8), a, acc[5]);
  acc[6] = fmaf((float)(signed char)(hi >> 16), a, acc[6]);
  acc[7] = fmaf((float)(hi >> 24), a, acc[7]);
}

// ---------------- fused dtype probe + weight pre-pack (one launch, 256 thr) ----------------
__global__ __launch_bounds__(256) void k_detect_pack(const int* __restrict__ edge,
                                                     const unsigned* __restrict__ xw,
                                                     const void* __restrict__ W_enc,
                                                     const void* __restrict__ W_gat,
                                                     int* __restrict__ flag,
                                                     short* __restrict__ packE,
                                                     short* __restrict__ packG) {
  __shared__ int sflag[2];
  int tid = threadIdx.x;
  if (tid < 64) {
    int v = edge[2 * tid + 1];
    unsigned long long nz = __ballot(v != 0);
    int bad = 0;
#pragma unroll
    for (int j = 0; j < 4; ++j) {
      unsigned w = xw[tid * 4 + j];
      unsigned ex = ((w & 0xFFFFu) >> 7) & 0xFFu;
      if (ex >= 0x90u) bad = 1;  // |bf16| >= 2^17: impossible for real x (~N(0,1))
    }
    unsigned long long anybad = __ballot(bad != 0);
    if (tid == 0) {
      sflag[0] = (nz == 0ULL) ? 1 : 0;
      sflag[1] = (anybad != 0ULL) ? 1 : 0;
      flag[0] = sflag[0];
      flag[1] = sflag[1];
    }
  }
  __syncthreads();
  int f32 = sflag[1];
  int wv = tid >> 6, lane = tid & 63;
  int quad = lane >> 4, m16 = lane & 15;
#pragma unroll
  for (int ks = 0; ks < 4; ++ks)
#pragma unroll
    for (int j = 0; j < 8; ++j)
      packE[(ks * 256 + tid) * 8 + j] =
          f2bfbits(ldf(W_enc, (ks * 32 + quad * 8 + j) * NHID + wv * 16 + m16, f32));
#pragma unroll
  for (int t = 0; t < 4; ++t)
#pragma unroll
    for (int ks = 0; ks < 2; ++ks)
#pragma unroll
      for (int j = 0; j < 8; ++j)
        packG[((t * 2 + ks) * 256 + tid) * 8 + j] =
            f2bfbits(ldf(W_gat, (ks * 32 + quad * 8 + j) * HD + wv * 64 + t * 16 + m16, f32));
}

// ---------------- CSR build ----------------
__global__ void k_hist(const int* __restrict__ edge, const int* __restrict__ flag,
                       int* __restrict__ counts) {
  int e = blockIdx.x * blockDim.x + threadIdx.x;
  if (e < N_EDGES) {
    int d = clampn(eload(edge, flag[0], N_EDGES + e));
    atomicAdd(&counts[d], 1);
  }
}

__global__ __launch_bounds__(1024) void k_scan(const int* __restrict__ counts,
                                               int* __restrict__ rowptr,
                                               int* __restrict__ cursor) {
  __shared__ int part[1024];
  int t = threadIdx.x;
  const int CH = (N_NODES + 1023) / 1024;  // 20
  int b = t * CH, e = min(b + CH, N_NODES);
  int s = 0;
  for (int i = b; i < e; ++i) s += counts[i];
  part[t] = s;
  __syncthreads();
  for (int off = 1; off < 1024; off <<= 1) {
    int v = (t >= off) ? part[t - off] : 0;
    __syncthreads();
    part[t] += v;
    __syncthreads();
  }
  int run = (t == 0) ? 0 : part[t - 1];
  for (int i = b; i < e; ++i) {
    rowptr[i] = run;
    cursor[i] = run;
    run += counts[i];
  }
  if (t == 1023) rowptr[N_NODES] = N_EDGES;
}

__global__ void k_scatter(const int* __restrict__ edge, const int* __restrict__ flag,
                          int* __restrict__ cursor, int* __restrict__ ssort) {
  int e = blockIdx.x * blockDim.x + threadIdx.x;
  if (e < N_EDGES) {
    int is64 = flag[0];
    int s = clampn(eload(edge, is64, e));
    int d = clampn(eload(edge, is64, N_EDGES + e));
    int pos = atomicAdd(&cursor[d], 1);
    if (pos >= 0 && pos < N_EDGES) ssort[pos] = s;
  }
}

// ---------------- encoder (MFMA, packed W): Y = relu(x @ W_enc + b_enc); X = Y ----------------
__global__ __launch_bounds__(256) void k_encoder(const void* __restrict__ x,
                                                 const short* __restrict__ packE,
                                                 const void* __restrict__ b_enc,
                                                 const int* __restrict__ flag,
                                                 float* __restrict__ X, float* __restrict__ Y) {
  int f32 = flag[1];
  int tid = threadIdx.x;
  int wv = tid >> 6, lane = tid & 63;
  int quad = lane >> 4, m16 = lane & 15;
  int n0 = blockIdx.x * 16;
  int c0 = wv * 16;

  float4v acc = {0.f, 0.f, 0.f, 0.f};
#pragma unroll
  for (int ks = 0; ks < 4; ++ks) {
    short8 bfrag = *(const short8*)(packE + (ks * 256 + tid) * 8);
    short8 afrag;
    size_t xoff = (size_t)(n0 + m16) * NFEAT + ks * 32 + quad * 8;
    if (f32) {
      float4 f0 = *(const float4*)((const float*)x + xoff);
      float4 f1 = *(const float4*)((const float*)x + xoff + 4);
      afrag[0] = f2bfbits(f0.x); afrag[1] = f2bfbits(f0.y);
      afrag[2] = f2bfbits(f0.z); afrag[3] = f2bfbits(f0.w);
      afrag[4] = f2bfbits(f1.x); afrag[5] = f2bfbits(f1.y);
      afrag[6] = f2bfbits(f1.z); afrag[7] = f2bfbits(f1.w);
    } else {
      afrag = *(const short8*)((const short*)x + xoff);
    }
    acc = __builtin_amdgcn_mfma_f32_16x16x32_bf16(afrag, bfrag, acc, 0, 0, 0);
  }

  float bias = ldf(b_enc, c0 + m16, f32);
#pragma unroll
  for (int r = 0; r < 4; ++r) {
    int n = n0 + quad * 4 + r;
    float yv = fmaxf(acc[r] + bias, 0.f);
    size_t idx = (size_t)n * NHID + c0 + m16;
    X[idx] = yv;
    Y[idx] = yv;
  }
}

// ---------------- per-layer projection (MFMA): h = X @ W_gat -> int8 row-scaled ----------------
// nodeinfo[n*8 + h*2] = a_src[n][h]; nodeinfo[n*8 + h*2 + 1] = row scale (32 B/node).
__global__ __launch_bounds__(256) void k_proj(const float* __restrict__ X,
                                              const short* __restrict__ packG,
                                              const void* __restrict__ att_src,
                                              const void* __restrict__ att_dst,
                                              const int* __restrict__ flag,
                                              signed char* __restrict__ hb,
                                              float* __restrict__ nodeinfo,
                                              float* __restrict__ a_dst) {
  __shared__ float smax[4][16];  // [wave][row-in-tile]
  int f32 = flag[1];
  int tid = threadIdx.x;
  int wv = tid >> 6, lane = tid & 63;
  int quad = lane >> 4, m16 = lane & 15;
  int n0 = blockIdx.x * 16;

  short8 afrag[2];
#pragma unroll
  for (int ks = 0; ks < 2; ++ks) {
    size_t xoff = (size_t)(n0 + m16) * NHID + ks * 32 + quad * 8;
    float4 f0 = *(const float4*)(X + xoff);
    float4 f1 = *(const float4*)(X + xoff + 4);
    afrag[ks][0] = f2bfbits(f0.x); afrag[ks][1] = f2bfbits(f0.y);
    afrag[ks][2] = f2bfbits(f0.z); afrag[ks][3] = f2bfbits(f0.w);
    afrag[ks][4] = f2bfbits(f1.x); afrag[ks][5] = f2bfbits(f1.y);
    afrag[ks][6] = f2bfbits(f1.z); afrag[ks][7] = f2bfbits(f1.w);
  }

  float4v acc[4];
#pragma unroll
  for (int t = 0; t < 4; ++t) {
    acc[t] = (float4v){0.f, 0.f, 0.f, 0.f};
#pragma unroll
    for (int ks = 0; ks < 2; ++ks) {
      short8 bfrag = *(const short8*)(packG + ((t * 2 + ks) * 256 + tid) * 8);
      acc[t] = __builtin_amdgcn_mfma_f32_16x16x32_bf16(afrag[ks], bfrag, acc[t], 0, 0, 0);
    }
  }

  // per-row absmax: reduce over t (local), m16 lanes (shfl), then waves (LDS)
  float amax[4];
#pragma unroll
  for (int r = 0; r < 4; ++r) {
    float m = fmaxf(fmaxf(fabsf(acc[0][r]), fabsf(acc[1][r])),
                    fmaxf(fabsf(acc[2][r]), fabsf(acc[3][r])));
#pragma unroll
    for (int sh = 1; sh < 16; sh <<= 1) m = fmaxf(m, __shfl_xor(m, sh, 64));
    amax[r] = m;
  }
  if (m16 == 0) {
#pragma unroll
    for (int r = 0; r < 4; ++r) smax[wv][quad * 4 + r] = amax[r];
  }
  __syncthreads();
  float inv[4], rmax[4];
#pragma unroll
  for (int r = 0; r < 4; ++r) {
    int row = quad * 4 + r;
    float m = fmaxf(fmaxf(smax[0][row], smax[1][row]), fmaxf(smax[2][row], smax[3][row]));
    rmax[r] = m;
    inv[r] = (m > 0.f) ? 127.f / m : 0.f;
  }

  float avs[4], avd[4];
#pragma unroll
  for (int t = 0; t < 4; ++t) {
    avs[t] = ldf(att_src, wv * 64 + t * 16 + m16, f32);
    avd[t] = ldf(att_dst, wv * 64 + t * 16 + m16, f32);
  }
  float ps[4], pd[4];
#pragma unroll
  for (int r = 0; r < 4; ++r) { ps[r] = 0.f; pd[r] = 0.f; }
#pragma unroll
  for (int t = 0; t < 4; ++t) {
#pragma unroll
    for (int r = 0; r < 4; ++r) {
      int n = n0 + quad * 4 + r;
      hb[(size_t)n * HD + wv * 64 + t * 16 + m16] =
          (signed char)__float2int_rn(acc[t][r] * inv[r]);
      ps[r] = fmaf(acc[t][r], avs[t], ps[r]);
      pd[r] = fmaf(acc[t][r], avd[t], pd[r]);
    }
  }
#pragma unroll
  for (int r = 0; r < 4; ++r) {
    float s = qsum(ps[r]);
    float dq = qsum(pd[r]);
    if (m16 == 0) {
      int n = n0 + quad * 4 + r;
      nodeinfo[(size_t)n * 8 + wv * 2] = s;
      nodeinfo[(size_t)n * 8 + wv * 2 + 1] = rmax[r] * (1.f / 127.f);
      a_dst[n * HEADS + wv] = dq;
    }
  }
}

// ---------------- per-layer: single-pass softmax-aggregate + ELU + mean + GraphCON + rms ----------------
// Per edge: one 8-B nodeinfo load (logit+scale, 1 line/edge) + one 8-B hb load; weight
// computed inline; denominator accumulated in the same loop (1 shfl at the end).
__global__ __launch_bounds__(256) void k_layer(const signed char* __restrict__ hb,
                                               const float* __restrict__ nodeinfo,
                                               const float* __restrict__ a_dst,
                                               const int* __restrict__ rowptr,
                                               const int* __restrict__ srcs,
                                               const void* __restrict__ b_gat,
                                               const int* __restrict__ flag,
                                               float* __restrict__ X, float* __restrict__ Y) {
  int wave = threadIdx.x >> 6, lane = threadIdx.x & 63;
  int half = lane >> 5, l32 = lane & 31, head = l32 >> 3;
  int f32 = flag[1];
  int d = blockIdx.x * 4 + wave;
  if (d >= N_NODES) return;
  int beg = rowptr[d];
  int end = rowptr[d + 1];
  beg = min(max(beg, 0), N_EDGES);
  end = min(max(end, beg), N_EDGES);
  float advh = a_dst[d * 4 + head];

  float acc[8];
#pragma unroll
  for (int k = 0; k < 8; ++k) acc[k] = 0.f;
  float sw = 0.f;

  {  // self loop, half 0 only (summed in via the cross-half combine)
    float2 nid = *(const float2*)(nodeinfo + (size_t)d * 8 + head * 2);
    float wself = __expf(lrelu(nid.x + advh));
    if (half == 0) {
      sw = wself;
      uint2 hv = *(const uint2*)(hb + (size_t)d * HD + l32 * 8);
      acc8_i8(acc, (int)hv.x, (int)hv.y, wself * nid.y);
    }
  }
  int p = beg;
  for (; p + 8 <= end; p += 8) {
    int q0 = p + half, q1 = p + 2 + half, q2 = p + 4 + half, q3 = p + 6 + half;
    int s0 = clampn(srcs[q0]), s1 = clampn(srcs[q1]);
    int s2 = clampn(srcs[q2]), s3 = clampn(srcs[q3]);
    float2 n0v = *(const float2*)(nodeinfo + (size_t)s0 * 8 + head * 2);
    float2 n1v = *(const float2*)(nodeinfo + (size_t)s1 * 8 + head * 2);
    float2 n2v = *(const float2*)(nodeinfo + (size_t)s2 * 8 + head * 2);
    float2 n3v = *(const float2*)(nodeinfo + (size_t)s3 * 8 + head * 2);
    uint2 h0 = *(const uint2*)(hb + (size_t)s0 * HD + l32 * 8);
    uint2 h1 = *(const uint2*)(hb + (size_t)s1 * HD + l32 * 8);
    uint2 h2 = *(const uint2*)(hb + (size_t)s2 * HD + l32 * 8);
    uint2 h3 = *(const uint2*)(hb + (size_t)s3 * HD + l32 * 8);
    float w0 = __expf(lrelu(n0v.x + advh));
    float w1 = __expf(lrelu(n1v.x + advh));
    float w2 = __expf(lrelu(n2v.x + advh));
    float w3 = __expf(lrelu(n3v.x + advh));
    sw += w0 + w1 + w2 + w3;
    acc8_i8(acc, (int)h0.x, (int)h0.y, w0 * n0v.y);
    acc8_i8(acc, (int)h1.x, (int)h1.y, w1 * n1v.y);
    acc8_i8(acc, (int)h2.x, (int)h2.y, w2 * n2v.y);
    acc8_i8(acc, (int)h3.x, (int)h3.y, w3 * n3v.y);
  }
  for (; p < end; p += 2) {
    int q = p + half;
    bool act = q < end;
    int s = clampn(srcs[act ? q : end - 1]);
    float2 nv = *(const float2*)(nodeinfo + (size_t)s * 8 + head * 2);
    uint2 hv = *(const uint2*)(hb + (size_t)s * HD + l32 * 8);
    float w = act ? __expf(lrelu(nv.x + advh)) : 0.f;
    sw += w;
    acc8_i8(acc, (int)hv.x, (int)hv.y, w * nv.y);
  }
  // combine halves (each accumulated its own edge subset; sum = total)
  sw += __shfl_xor(sw, 32, 64);
#pragma unroll
  for (int k = 0; k < 8; ++k) acc[k] += __shfl_xor(acc[k], 32, 64);
  float invh = 1.f / (sw + 1e-16f);

  // normalize + bias + ELU + mean-over-4: lane owns mean groups 2*l32, 2*l32+1
  float cg[8];
#pragma unroll
  for (int k = 0; k < 8; ++k) {
    float c = acc[k] * invh + ldf(b_gat, l32 * 8 + k, f32);
    cg[k] = c > 0.f ? c : expm1f(c);
  }
  float agg0 = 0.25f * (cg[0] + cg[1] + cg[2] + cg[3]);
  float agg1 = 0.25f * (cg[4] + cg[5] + cg[6] + cg[7]);

  // GraphCON update for hidden dims 2*l32, 2*l32+1
  size_t ix = (size_t)d * NHID + l32 * 2;
  float xv0 = X[ix], xv1 = X[ix + 1];
  float yv0 = Y[ix], yv1 = Y[ix + 1];
  float yn0 = yv0 + (SP1 * agg0 - 2.f * SP1 * SP1 * yv0 - SP1 * SP1 * xv0);
  float yn1 = yv1 + (SP1 * agg1 - 2.f * SP1 * SP1 * yv1 - SP1 * SP1 * xv1);
  float xn0 = xv0 + yn0;
  float xn1 = xv1 + yn1;

  // rms_norm (halves duplicated -> divide by 128)
  float msx = wsum(xn0 * xn0 + xn1 * xn1) * (1.f / 128.f);
  float rx = rsqrtf(msx + EPSV);
  float msy = wsum(yn0 * yn0 + yn1 * yn1) * (1.f / 128.f);
  float ry = rsqrtf(msy + EPSV);
  X[ix] = xn0 * rx; X[ix + 1] = xn1 * rx;
  Y[ix] = yn0 * ry; Y[ix + 1] = yn1 * ry;
}

// ---------------- decoder: out = X @ W_dec + b_dec (fp32 output) ----------------
__global__ __launch_bounds__(256) void k_dec(const float* __restrict__ X,
                                             const void* __restrict__ W_dec,
                                             const void* __restrict__ b_dec,
                                             const int* __restrict__ flag,
                                             float* __restrict__ out) {
  __shared__ float Wl[NHID * NCLASS];
  __shared__ float bl[NCLASS];
  int f32 = flag[1];
  int tid = threadIdx.x;
  for (int i = tid; i < NHID * NCLASS; i += 256) Wl[i] = ldf(W_dec, i, f32);
  if (tid < NCLASS) bl[tid] = ldf(b_dec, tid, f32);
  __syncthreads();
  int g = blockIdx.x * 256 + tid;
  if (g >= N_NODES * NCLASS) return;
  int n = g >> 4, c = g & 15;
  const float* xr = X + (size_t)n * NHID;
  float acc = bl[c];
#pragma unroll
  for (int k = 0; k < NHID; ++k) acc = fmaf(xr[k], Wl[k * NCLASS + c], acc);
  if (!(acc == acc) || fabsf(acc) > 1e6f) acc = 777.0f;
  out[g] = acc;
}

extern "C" void kernel_launch(void* const* d_in, const int* in_sizes, int n_in,
                              void* d_out, int out_size, void* d_ws, size_t ws_size,
                              hipStream_t stream) {
  const void* x       = d_in[0];
  const int*  edge    = (const int*)d_in[1];
  const void* W_enc   = d_in[2];
  const void* b_enc   = d_in[3];
  const void* W_gat   = d_in[4];
  const void* att_src = d_in[5];
  const void* att_dst = d_in[6];
  const void* b_gat   = d_in[7];
  const void* W_dec   = d_in[8];
  const void* b_dec   = d_in[9];

  char* ws = (char*)d_ws;
  size_t off = 0;
  auto alloc = [&](size_t bytes) -> void* {
    if (off + bytes > ws_size) off = 0;  // wrap: aliasing beats foreign-memory corruption
    void* p = ws + off;
    off = (off + bytes + 255) & ~(size_t)255;
    return p;
  };
  int*   flag    = (int*)alloc(256);
  int*   counts  = (int*)alloc((size_t)N_NODES * 4);
  int*   rowptr  = (int*)alloc((size_t)(N_NODES + 1) * 4);
  int*   cursor  = (int*)alloc((size_t)N_NODES * 4);
  int*   ssort   = (int*)alloc((size_t)N_EDGES * 4);
  float* nodeinfo= (float*)alloc((size_t)N_NODES * 8 * 4);   // 640 KB
  float* a_dst   = (float*)alloc((size_t)N_NODES * HEADS * 4);
  float* X       = (float*)alloc((size_t)N_NODES * NHID * 4);
  float* Y       = (float*)alloc((size_t)N_NODES * NHID * 4);
  short* packE   = (short*)alloc((size_t)4 * 256 * 8 * 2);   // 16 KB
  short* packG   = (short*)alloc((size_t)8 * 256 * 8 * 2);   // 32 KB
  signed char* hb = (signed char*)alloc((size_t)N_NODES * HD);  // int8 h (5.12 MB)

  hipMemsetAsync(counts, 0, (size_t)N_NODES * 4, stream);
  k_detect_pack<<<1, 256, 0, stream>>>(edge, (const unsigned*)x, W_enc, W_gat, flag, packE, packG);
  k_hist<<<(N_EDGES + 255) / 256, 256, 0, stream>>>(edge, flag, counts);
  k_scan<<<1, 1024, 0, stream>>>(counts, rowptr, cursor);
  k_scatter<<<(N_EDGES + 255) / 256, 256, 0, stream>>>(edge, flag, cursor, ssort);

  k_encoder<<<N_NODES / 16, 256, 0, stream>>>(x, packE, b_enc, flag, X, Y);
  for (int l = 0; l < 3; ++l) {
    k_proj<<<N_NODES / 16, 256, 0, stream>>>(X, packG, att_src, att_dst, flag, hb, nodeinfo, a_dst);
    k_layer<<<N_NODES / 4, 256, 0, stream>>>(hb, nodeinfo, a_dst, rowptr, ssort, b_gat, flag, X, Y);
  }
  k_dec<<<(N_NODES * NCLASS + 255) / 256, 256, 0, stream>>>(X, W_dec, b_dec, flag, (float*)d_out);
}